// Round 1
// baseline (1404.235 us; speedup 1.0000x reference)
//
#include <hip/hip_runtime.h>
#include <math.h>

#ifndef M_PI
#define M_PI 3.14159265358979323846
#endif

#define BB 64
#define HH 512
#define WW 512
#define NPIX (HH*WW)        // 262144
#define NHIST 65536
#define MED_K 131072u       // (k+1) where k = (n-1)//2 = 131071, 1-indexed rank

__device__ __forceinline__ float2 cmulf(float2 a, float2 b){
  return make_float2(a.x*b.x - a.y*b.y, a.x*b.y + a.y*b.x);
}
__device__ __forceinline__ unsigned rev9(unsigned v){ return __brev(v) >> 23; }

// ---------------- FFT kernels ----------------
// 512-point radix-2 DIT FFT in LDS, 256 threads (one butterfly each per stage).
// Twiddles exp(-2*pi*i*r/512), r in [0,256), computed once per block in double.

__global__ __launch_bounds__(256) void row_fft_kernel(const float* __restrict__ x,
                                                      float2* __restrict__ out){
  __shared__ float2 s[512];
  __shared__ float2 tw[256];
  int t = threadIdx.x;
  {
    double a = -2.0 * M_PI * (double)t / 512.0;
    tw[t] = make_float2((float)cos(a), (float)sin(a));
  }
  int row = blockIdx.x;               // b*512 + h
  int b = row >> 9;
  const float* rp = x + (size_t)b*3*NPIX + (size_t)(row & 511)*WW;
  const float* gp = rp + NPIX;
  const float* bp = rp + 2*NPIX;
  for (int k = t; k < 512; k += 256){
    float g = 0.299f*rp[k] + 0.587f*gp[k] + 0.114f*bp[k];
    s[rev9((unsigned)k)] = make_float2(g, 0.f);
  }
  __syncthreads();
  #pragma unroll
  for (int st = 1; st <= 9; ++st){
    int half = 1 << (st-1);
    int k = t & (half - 1);
    int i1 = ((t >> (st-1)) << st) + k;
    int i2 = i1 + half;
    float2 w = tw[k << (9 - st)];
    float2 u = s[i1];
    float2 v = cmulf(w, s[i2]);
    s[i1] = make_float2(u.x + v.x, u.y + v.y);
    s[i2] = make_float2(u.x - v.x, u.y - v.y);
    __syncthreads();
  }
  float2* o = out + (size_t)row*WW;
  for (int k = t; k < 512; k += 256) o[k] = s[k];
}

__global__ __launch_bounds__(256) void col_fft_kernel(const float2* __restrict__ in,
                                                      float* __restrict__ mag,
                                                      unsigned* __restrict__ dmax){
  __shared__ float2 s[512];
  __shared__ float2 tw[256];
  __shared__ float red[256];
  int t = threadIdx.x;
  {
    double a = -2.0 * M_PI * (double)t / 512.0;
    tw[t] = make_float2((float)cos(a), (float)sin(a));
  }
  int cid = blockIdx.x;               // b*512 + j
  int b = cid >> 9, j = cid & 511;
  const float2* base = in + (size_t)b*NPIX + j;
  for (int k = t; k < 512; k += 256) s[rev9((unsigned)k)] = base[(size_t)k*WW];
  __syncthreads();
  #pragma unroll
  for (int st = 1; st <= 9; ++st){
    int half = 1 << (st-1);
    int k = t & (half - 1);
    int i1 = ((t >> (st-1)) << st) + k;
    int i2 = i1 + half;
    float2 w = tw[k << (9 - st)];
    float2 u = s[i1];
    float2 v = cmulf(w, s[i2]);
    s[i1] = make_float2(u.x + v.x, u.y + v.y);
    s[i2] = make_float2(u.x - v.x, u.y - v.y);
    __syncthreads();
  }
  int sj = (j + 256) & 511;           // fftshift along W
  float* mo = mag + (size_t)b*NPIX + sj;
  float lmax = 0.f;
  for (int k = t; k < 512; k += 256){
    float2 v = s[k];
    float m = sqrtf(v.x*v.x + v.y*v.y) + 1e-8f;
    int si = (k + 256) & 511;         // fftshift along H
    mo[(size_t)si*WW] = m;
    lmax = fmaxf(lmax, m);
  }
  red[t] = lmax; __syncthreads();
  for (int o = 128; o > 0; o >>= 1){
    if (t < o) red[t] = fmaxf(red[t], red[t+o]);
    __syncthreads();
  }
  if (t == 0) atomicMax(dmax + b, __float_as_uint(red[0]));  // positive floats: bit order == value order
}

// ---------------- reductions ----------------

__device__ double block_red_add_d(double v, double* buf){
  int t = threadIdx.x;
  buf[t] = v; __syncthreads();
  for (int o = 128; o > 0; o >>= 1){ if (t < o) buf[t] += buf[t+o]; __syncthreads(); }
  double r = buf[0]; __syncthreads(); return r;
}
__device__ double block_red_min_d(double v, double* buf){
  int t = threadIdx.x;
  buf[t] = v; __syncthreads();
  for (int o = 128; o > 0; o >>= 1){ if (t < o) buf[t] = fmin(buf[t], buf[t+o]); __syncthreads(); }
  double r = buf[0]; __syncthreads(); return r;
}

// Pass A: sum, sumsq, min, cnt>0.5d, cnt>0.1d, quadrant sums (all on raw mag)
__global__ __launch_bounds__(256) void stats_kernel(const float* __restrict__ mag,
    const unsigned* __restrict__ dmax,
    double* __restrict__ sum, double* __restrict__ sumsq, double* __restrict__ qsum,
    unsigned* __restrict__ dmin, unsigned* __restrict__ cnt_half, unsigned* __restrict__ cnt_tenth)
{
  __shared__ double buf[256];
  int b = blockIdx.x;
  int t = threadIdx.x;
  const float* p = mag + (size_t)b*NPIX;
  float d = __uint_as_float(dmax[b]) + 1e-8f;
  float th = 0.5f*d, tt = 0.1f*d;
  int per = NPIX / gridDim.y;
  int st0 = blockIdx.y * per;
  double lsum = 0.0, lsq = 0.0;
  double lq[4] = {0,0,0,0};
  float lmn = 3.4e38f;
  unsigned lh = 0, lt = 0;
  for (int i = st0 + t; i < st0 + per; i += 256){
    float v = p[i];
    lsum += (double)v;
    lsq  += (double)v * (double)v;
    lmn = fminf(lmn, v);
    lh += (v > th) ? 1u : 0u;
    lt += (v > tt) ? 1u : 0u;
    lq[i >> 16] += (double)v;          // row = i>>9, quadrant = row>>7
  }
  double rs = block_red_add_d(lsum, buf);
  double rq = block_red_add_d(lsq, buf);
  double r0 = block_red_add_d(lq[0], buf);
  double r1 = block_red_add_d(lq[1], buf);
  double r2 = block_red_add_d(lq[2], buf);
  double r3 = block_red_add_d(lq[3], buf);
  double rmn = block_red_min_d((double)lmn, buf);
  double rh = block_red_add_d((double)lh, buf);
  double rt = block_red_add_d((double)lt, buf);
  if (t == 0){
    atomicAdd(sum + b, rs);
    atomicAdd(sumsq + b, rq);
    atomicAdd(qsum + b*4 + 0, r0);
    atomicAdd(qsum + b*4 + 1, r1);
    atomicAdd(qsum + b*4 + 2, r2);
    atomicAdd(qsum + b*4 + 3, r3);
    atomicMin(dmin + b, __float_as_uint((float)rmn));
    atomicAdd(cnt_half + b, (unsigned)rh);
    atomicAdd(cnt_tenth + b, (unsigned)rt);
  }
}

// Median pass 1: histogram of top 16 bits of the float bit pattern (all values > 0)
__global__ __launch_bounds__(256) void hist_hi_kernel(const float* __restrict__ mag,
                                                      unsigned* __restrict__ hist){
  int b = blockIdx.x;
  const float* p = mag + (size_t)b*NPIX;
  unsigned* hb = hist + (size_t)b*NHIST;
  int per = NPIX / gridDim.y;
  int st0 = blockIdx.y * per;
  for (int i = st0 + threadIdx.x; i < st0 + per; i += 256){
    unsigned bits = __float_as_uint(p[i]);
    atomicAdd(&hb[bits >> 16], 1u);
  }
}

__global__ __launch_bounds__(256) void scan_hi_kernel(const unsigned* __restrict__ hist,
                                                      unsigned* __restrict__ sel,
                                                      unsigned* __restrict__ rank_rem){
  int b = blockIdx.x;
  const unsigned* hb = hist + (size_t)b*NHIST;
  __shared__ unsigned part[256];
  int t = threadIdx.x;
  unsigned s = 0;
  for (int i = 0; i < 256; ++i) s += hb[t*256 + i];
  part[t] = s; __syncthreads();
  if (t == 0){
    unsigned target = MED_K;
    unsigned cum = 0; int seg = 0;
    for (; seg < 256; ++seg){
      if (cum + part[seg] >= target) break;
      cum += part[seg];
    }
    unsigned rem = target - cum;
    int bin = seg*256;
    for (;; ++bin){
      unsigned c = hb[bin];
      if (c >= rem) break;
      rem -= c;
    }
    sel[b] = (unsigned)bin;
    rank_rem[b] = rem;
  }
}

// Median pass 2 (low 16 bits among matching hi) + gt_mean count (fused)
__global__ __launch_bounds__(256) void hist_lo_kernel(const float* __restrict__ mag,
    const unsigned* __restrict__ sel, const double* __restrict__ sum,
    unsigned* __restrict__ hist, unsigned* __restrict__ cnt_gtmean){
  int b = blockIdx.x;
  const float* p = mag + (size_t)b*NPIX;
  unsigned selhi = sel[b];
  float meanf = (float)(sum[b] * (1.0/(double)NPIX));  // raw-domain mean
  unsigned* hb = hist + (size_t)b*NHIST;
  int per = NPIX / gridDim.y;
  int st0 = blockIdx.y * per;
  unsigned lcnt = 0;
  for (int i = st0 + threadIdx.x; i < st0 + per; i += 256){
    float v = p[i];
    unsigned bits = __float_as_uint(v);
    if ((bits >> 16) == selhi) atomicAdd(&hb[bits & 0xffffu], 1u);
    lcnt += (v > meanf) ? 1u : 0u;
  }
  __shared__ unsigned rb[256];
  rb[threadIdx.x] = lcnt; __syncthreads();
  for (int o = 128; o > 0; o >>= 1){
    if (threadIdx.x < o) rb[threadIdx.x] += rb[threadIdx.x + o];
    __syncthreads();
  }
  if (threadIdx.x == 0) atomicAdd(cnt_gtmean + b, rb[0]);
}

__global__ __launch_bounds__(256) void scan_lo_kernel(const unsigned* __restrict__ hist,
    const unsigned* __restrict__ sel, const unsigned* __restrict__ rank_rem,
    unsigned* __restrict__ medbits){
  int b = blockIdx.x;
  const unsigned* hb = hist + (size_t)b*NHIST;
  __shared__ unsigned part[256];
  int t = threadIdx.x;
  unsigned s = 0;
  for (int i = 0; i < 256; ++i) s += hb[t*256 + i];
  part[t] = s; __syncthreads();
  if (t == 0){
    unsigned target = rank_rem[b];
    unsigned cum = 0; int seg = 0;
    for (; seg < 256; ++seg){
      if (cum + part[seg] >= target) break;
      cum += part[seg];
    }
    unsigned rem = target - cum;
    int bin = seg*256;
    for (;; ++bin){
      unsigned c = hb[bin];
      if (c >= rem) break;
      rem -= c;
    }
    medbits[b] = (sel[b] << 16) | (unsigned)bin;
  }
}

// ---------------- features ----------------
__global__ void feats_kernel(const unsigned* __restrict__ dmax, const unsigned* __restrict__ dmin,
    const double* __restrict__ sum, const double* __restrict__ sumsq, const double* __restrict__ qsum,
    const unsigned* __restrict__ cnt_half, const unsigned* __restrict__ cnt_tenth,
    const unsigned* __restrict__ cnt_gtmean, const unsigned* __restrict__ medbits,
    float* __restrict__ feats)
{
  int b = threadIdx.x;
  if (b >= BB) return;
  float maxv = __uint_as_float(dmax[b]);
  float d = maxv + 1e-8f;              // f32 add, matching reference
  double dd = (double)d;
  double n = (double)NPIX;
  double sm = sum[b] / dd;             // sum of normalized m
  double sq = sumsq[b] / (dd*dd);      // sum of m^2
  double mean = sm / n;
  double var = (sq - sm*sm/n) / (n - 1.0);
  if (var < 0.0) var = 0.0;
  float stdv = (float)sqrt(var);
  if (stdv < 1e-8f) stdv = 1e-8f;
  float mx = maxv / d;
  float mn = __uint_as_float(dmin[b]) / d;
  float gtm = (float)((double)cnt_gtmean[b] / n);
  float med = __uint_as_float(medbits[b]) / d;
  float q0 = (float)(qsum[b*4+0] / dd * (1.0/65536.0));
  float q1 = (float)(qsum[b*4+1] / dd * (1.0/65536.0));
  float q2 = (float)(qsum[b*4+2] / dd * (1.0/65536.0));
  float q3 = (float)(qsum[b*4+3] / dd * (1.0/65536.0));
  float gh = (float)((double)cnt_half[b] / n);
  float gt = (float)((double)cnt_tenth[b] / n);
  float f[12] = {(float)mean, stdv, mx, mn, gtm, med, q0, q1, q2, q3, gh, gt};
  #pragma unroll
  for (int i = 0; i < 12; ++i){
    float v = f[i];
    v = fminf(fmaxf(v, -10.f), 10.f);
    feats[b*12 + i] = v;
  }
}

// ---------------- MLP (single block) ----------------
__global__ __launch_bounds__(512) void mlp_kernel(const float* __restrict__ feats,
    const float* __restrict__ W1, const float* __restrict__ b1,
    const float* __restrict__ g1, const float* __restrict__ be1,
    const float* __restrict__ W2, const float* __restrict__ b2,
    const float* __restrict__ g2, const float* __restrict__ be2,
    const float* __restrict__ W3, const float* __restrict__ b3,
    float* __restrict__ out)
{
  __shared__ float f[BB*12];
  __shared__ float h1[BB*64];
  __shared__ float h2[BB*128];
  __shared__ float scale[128], shift[128];
  int t = threadIdx.x;
  const int nt = 512;
  for (int i = t; i < BB*12; i += nt) f[i] = feats[i];
  __syncthreads();
  // layer 1: [64,12] @ [12,64] + b1
  for (int i = t; i < BB*64; i += nt){
    int r = i >> 6, c = i & 63;
    float acc = b1[c];
    #pragma unroll
    for (int k = 0; k < 12; ++k) acc += f[r*12 + k] * W1[k*64 + c];
    h1[i] = acc;
  }
  __syncthreads();
  // BN1 (batch stats, biased var, eps=1e-5)
  if (t < 64){
    float mu = 0.f;
    for (int r = 0; r < BB; ++r) mu += h1[r*64 + t];
    mu *= (1.f/BB);
    float var = 0.f;
    for (int r = 0; r < BB; ++r){ float dd = h1[r*64 + t] - mu; var += dd*dd; }
    var *= (1.f/BB);
    float sc = g1[t] / sqrtf(var + 1e-5f);
    scale[t] = sc; shift[t] = be1[t] - mu*sc;
  }
  __syncthreads();
  for (int i = t; i < BB*64; i += nt){
    int c = i & 63;
    float v = h1[i]*scale[c] + shift[c];
    h1[i] = v > 0.f ? v : 0.f;
  }
  __syncthreads();
  // layer 2: [64,64] @ [64,128] + b2
  for (int i = t; i < BB*128; i += nt){
    int r = i >> 7, c = i & 127;
    float acc = b2[c];
    for (int k = 0; k < 64; ++k) acc += h1[r*64 + k] * W2[k*128 + c];
    h2[i] = acc;
  }
  __syncthreads();
  if (t < 128){
    float mu = 0.f;
    for (int r = 0; r < BB; ++r) mu += h2[r*128 + t];
    mu *= (1.f/BB);
    float var = 0.f;
    for (int r = 0; r < BB; ++r){ float dd = h2[r*128 + t] - mu; var += dd*dd; }
    var *= (1.f/BB);
    float sc = g2[t] / sqrtf(var + 1e-5f);
    scale[t] = sc; shift[t] = be2[t] - mu*sc;
  }
  __syncthreads();
  for (int i = t; i < BB*128; i += nt){
    int c = i & 127;
    float v = h2[i]*scale[c] + shift[c];
    h2[i] = v > 0.f ? v : 0.f;
  }
  __syncthreads();
  // layer 3: [64,128] @ [128,512] + b3
  for (int i = t; i < BB*512; i += nt){
    int r = i >> 9, c = i & 511;
    float acc = b3[c];
    for (int k = 0; k < 128; ++k) acc += h2[r*128 + k] * W3[k*512 + c];
    out[i] = acc;
  }
}

// ---------------- launch ----------------
extern "C" void kernel_launch(void* const* d_in, const int* in_sizes, int n_in,
                              void* d_out, int out_size, void* d_ws, size_t ws_size,
                              hipStream_t stream) {
  (void)in_sizes; (void)n_in; (void)out_size; (void)ws_size;
  const float* x   = (const float*)d_in[0];
  const float* W1  = (const float*)d_in[1];
  const float* b1  = (const float*)d_in[2];
  const float* g1  = (const float*)d_in[3];
  const float* be1 = (const float*)d_in[4];
  const float* W2  = (const float*)d_in[5];
  const float* b2  = (const float*)d_in[6];
  const float* g2  = (const float*)d_in[7];
  const float* be2 = (const float*)d_in[8];
  const float* W3  = (const float*)d_in[9];
  const float* b3  = (const float*)d_in[10];
  float* out = (float*)d_out;

  char* ws = (char*)d_ws;
  // layout: [0,128MB) complex row-FFT buffer (reused as histograms after col FFT)
  //         [128MB,192MB) shifted raw magnitude
  //         [192MB, +8KB) scalars
  float2* bufc = (float2*)ws;
  float* mag = (float*)(ws + 134217728);
  char* sc = ws + 201326592;
  unsigned* dmax      = (unsigned*)(sc + 0);
  unsigned* dmin      = (unsigned*)(sc + 256);
  double*   sum       = (double*)(sc + 512);
  double*   sumsq     = (double*)(sc + 1024);
  double*   qsum      = (double*)(sc + 1536);   // 64*4 doubles = 2048 B
  unsigned* cnt_half  = (unsigned*)(sc + 3584);
  unsigned* cnt_tenth = (unsigned*)(sc + 3840);
  unsigned* cnt_gtm   = (unsigned*)(sc + 4096);
  unsigned* sel_hi    = (unsigned*)(sc + 4352);
  unsigned* rank_rem  = (unsigned*)(sc + 4608);
  unsigned* medbits   = (unsigned*)(sc + 4864);
  float*    feats     = (float*)(sc + 5120);
  unsigned* hist      = (unsigned*)ws;          // 64*65536*4 = 16MB, reuses bufc

  hipMemsetAsync(sc, 0, 8192, stream);
  hipMemsetAsync(dmin, 0xFF, 256, stream);

  row_fft_kernel<<<BB*HH, 256, 0, stream>>>(x, bufc);
  col_fft_kernel<<<BB*WW, 256, 0, stream>>>(bufc, mag, dmax);

  hipMemsetAsync(hist, 0, (size_t)BB*NHIST*4, stream);   // bufc is dead now
  stats_kernel<<<dim3(BB, 8), 256, 0, stream>>>(mag, dmax, sum, sumsq, qsum, dmin, cnt_half, cnt_tenth);
  hist_hi_kernel<<<dim3(BB, 8), 256, 0, stream>>>(mag, hist);
  scan_hi_kernel<<<BB, 256, 0, stream>>>(hist, sel_hi, rank_rem);
  hipMemsetAsync(hist, 0, (size_t)BB*NHIST*4, stream);
  hist_lo_kernel<<<dim3(BB, 8), 256, 0, stream>>>(mag, sel_hi, sum, hist, cnt_gtm);
  scan_lo_kernel<<<BB, 256, 0, stream>>>(hist, sel_hi, rank_rem, medbits);

  feats_kernel<<<1, 64, 0, stream>>>(dmax, dmin, sum, sumsq, qsum, cnt_half, cnt_tenth, cnt_gtm, medbits, feats);
  mlp_kernel<<<1, 512, 0, stream>>>(feats, W1, b1, g1, be1, W2, b2, g2, be2, W3, b3, out);
}

// Round 2
// 913.946 us; speedup vs baseline: 1.5365x; 1.5365x over previous
//
#include <hip/hip_runtime.h>
#include <math.h>

#ifndef M_PI
#define M_PI 3.14159265358979323846
#endif

#define BB 64
#define HH 512
#define WW 512
#define NPIX (HH*WW)        // 262144
#define NSPLIT 16
#define MED_K 131072u       // 1-indexed rank of (n-1)//2

__device__ __forceinline__ float2 cmulf(float2 a, float2 b){
  return make_float2(a.x*b.x - a.y*b.y, a.x*b.y + a.y*b.x);
}
__device__ __forceinline__ unsigned rev9(unsigned v){ return __brev(v) >> 23; }

// ---------------- FFT kernels ----------------
__global__ __launch_bounds__(256) void row_fft_kernel(const float* __restrict__ x,
                                                      float2* __restrict__ out){
  __shared__ float2 s[512];
  __shared__ float2 tw[256];
  int t = threadIdx.x;
  {
    double a = -2.0 * M_PI * (double)t / 512.0;
    tw[t] = make_float2((float)cos(a), (float)sin(a));
  }
  int row = blockIdx.x;               // b*512 + h
  int b = row >> 9;
  const float* rp = x + (size_t)b*3*NPIX + (size_t)(row & 511)*WW;
  const float* gp = rp + NPIX;
  const float* bp = rp + 2*NPIX;
  for (int k = t; k < 512; k += 256){
    float g = 0.299f*rp[k] + 0.587f*gp[k] + 0.114f*bp[k];
    s[rev9((unsigned)k)] = make_float2(g, 0.f);
  }
  __syncthreads();
  #pragma unroll
  for (int st = 1; st <= 9; ++st){
    int half = 1 << (st-1);
    int k = t & (half - 1);
    int i1 = ((t >> (st-1)) << st) + k;
    int i2 = i1 + half;
    float2 w = tw[k << (9 - st)];
    float2 u = s[i1];
    float2 v = cmulf(w, s[i2]);
    s[i1] = make_float2(u.x + v.x, u.y + v.y);
    s[i2] = make_float2(u.x - v.x, u.y - v.y);
    __syncthreads();
  }
  float2* o = out + (size_t)row*WW;
  for (int k = t; k < 512; k += 256) o[k] = s[k];
}

__global__ __launch_bounds__(256) void col_fft_kernel(const float2* __restrict__ in,
                                                      float* __restrict__ mag,
                                                      unsigned* __restrict__ dmax){
  __shared__ float2 s[512];
  __shared__ float2 tw[256];
  __shared__ float red[256];
  int t = threadIdx.x;
  {
    double a = -2.0 * M_PI * (double)t / 512.0;
    tw[t] = make_float2((float)cos(a), (float)sin(a));
  }
  int cid = blockIdx.x;               // b*512 + j
  int b = cid >> 9, j = cid & 511;
  const float2* base = in + (size_t)b*NPIX + j;
  for (int k = t; k < 512; k += 256) s[rev9((unsigned)k)] = base[(size_t)k*WW];
  __syncthreads();
  #pragma unroll
  for (int st = 1; st <= 9; ++st){
    int half = 1 << (st-1);
    int k = t & (half - 1);
    int i1 = ((t >> (st-1)) << st) + k;
    int i2 = i1 + half;
    float2 w = tw[k << (9 - st)];
    float2 u = s[i1];
    float2 v = cmulf(w, s[i2]);
    s[i1] = make_float2(u.x + v.x, u.y + v.y);
    s[i2] = make_float2(u.x - v.x, u.y - v.y);
    __syncthreads();
  }
  int sj = (j + 256) & 511;           // fftshift along W
  float* mo = mag + (size_t)b*NPIX + sj;
  float lmax = 0.f;
  for (int k = t; k < 512; k += 256){
    float2 v = s[k];
    float m = sqrtf(v.x*v.x + v.y*v.y) + 1e-8f;
    int si = (k + 256) & 511;         // fftshift along H
    mo[(size_t)si*WW] = m;
    lmax = fmaxf(lmax, m);
  }
  red[t] = lmax; __syncthreads();
  for (int o = 128; o > 0; o >>= 1){
    if (t < o) red[t] = fmaxf(red[t], red[t+o]);
    __syncthreads();
  }
  if (t == 0) atomicMax(dmax + b, __float_as_uint(red[0]));
}

// ---------------- fused stats + radix pass 1 ----------------
// grid (BB, NSPLIT), 256 thr. Reads mag once: sum/sumsq/min/cnt_half/cnt_tenth/qsum
// + LDS 2048-bin histogram of bits[31:20].
__global__ __launch_bounds__(256) void pass1_kernel(const float4* __restrict__ mag4,
    const unsigned* __restrict__ dmax,
    double* __restrict__ sum, double* __restrict__ sumsq, double* __restrict__ qsum,
    unsigned* __restrict__ dmin, unsigned* __restrict__ cnt_half, unsigned* __restrict__ cnt_tenth,
    unsigned* __restrict__ hist1)
{
  __shared__ unsigned h[2048];
  __shared__ double buf[256];
  int t = threadIdx.x;
  int b = blockIdx.x;
  for (int i = t; i < 2048; i += 256) h[i] = 0;
  __syncthreads();
  float d = __uint_as_float(dmax[b]) + 1e-8f;
  float th = 0.5f*d, tt = 0.1f*d;
  const int perblk = (NPIX/4)/NSPLIT;          // 4096 float4 = 16384 scalars
  const float4* p = mag4 + (size_t)b*(NPIX/4) + (size_t)blockIdx.y*perblk;
  int quad = (int)((blockIdx.y*perblk*4) >> 16);  // block fully inside one quadrant
  double lsum = 0.0, lsq = 0.0;
  float lmn = 3.4e38f;
  unsigned lh = 0, lt = 0;
  for (int i = t; i < perblk; i += 256){
    float4 v = p[i];
    float a0=v.x, a1=v.y, a2=v.z, a3=v.w;
    lsum += (double)a0 + (double)a1 + (double)a2 + (double)a3;
    lsq  += (double)a0*(double)a0 + (double)a1*(double)a1
          + (double)a2*(double)a2 + (double)a3*(double)a3;
    lmn = fminf(lmn, fminf(fminf(a0,a1), fminf(a2,a3)));
    lh += (a0>th) + (a1>th) + (a2>th) + (a3>th);
    lt += (a0>tt) + (a1>tt) + (a2>tt) + (a3>tt);
    atomicAdd(&h[__float_as_uint(a0) >> 20], 1u);
    atomicAdd(&h[__float_as_uint(a1) >> 20], 1u);
    atomicAdd(&h[__float_as_uint(a2) >> 20], 1u);
    atomicAdd(&h[__float_as_uint(a3) >> 20], 1u);
  }
  // block reductions
  buf[t] = lsum; __syncthreads();
  for (int o = 128; o > 0; o >>= 1){ if (t < o) buf[t] += buf[t+o]; __syncthreads(); }
  double rs = buf[0]; __syncthreads();
  buf[t] = lsq; __syncthreads();
  for (int o = 128; o > 0; o >>= 1){ if (t < o) buf[t] += buf[t+o]; __syncthreads(); }
  double rq = buf[0]; __syncthreads();
  buf[t] = (double)lmn; __syncthreads();
  for (int o = 128; o > 0; o >>= 1){ if (t < o) buf[t] = fmin(buf[t], buf[t+o]); __syncthreads(); }
  double rmn = buf[0]; __syncthreads();
  buf[t] = (double)lh; __syncthreads();
  for (int o = 128; o > 0; o >>= 1){ if (t < o) buf[t] += buf[t+o]; __syncthreads(); }
  double rh = buf[0]; __syncthreads();
  buf[t] = (double)lt; __syncthreads();
  for (int o = 128; o > 0; o >>= 1){ if (t < o) buf[t] += buf[t+o]; __syncthreads(); }
  double rt = buf[0]; __syncthreads();
  if (t == 0){
    atomicAdd(sum + b, rs);
    atomicAdd(sumsq + b, rq);
    atomicAdd(qsum + b*4 + quad, rs);
    atomicMin(dmin + b, __float_as_uint((float)rmn));
    atomicAdd(cnt_half + b, (unsigned)rh);
    atomicAdd(cnt_tenth + b, (unsigned)rt);
  }
  // merge histogram
  unsigned* hb = hist1 + (size_t)b*2048;
  for (int i = t; i < 2048; i += 256){
    unsigned c = h[i];
    if (c) atomicAdd(&hb[i], c);
  }
}

__global__ void scan1_kernel(const unsigned* __restrict__ hist,
                             unsigned* __restrict__ sel, unsigned* __restrict__ rem){
  int b = blockIdx.x;
  const unsigned* hb = hist + (size_t)b*2048;
  __shared__ unsigned part[256];
  int t = threadIdx.x;
  unsigned s = 0;
  for (int i = 0; i < 8; ++i) s += hb[t*8 + i];
  part[t] = s; __syncthreads();
  if (t == 0){
    unsigned target = MED_K, cum = 0; int seg = 0;
    for (; seg < 256; ++seg){ if (cum + part[seg] >= target) break; cum += part[seg]; }
    unsigned r = target - cum;
    int bin = seg*8;
    for (;; ++bin){ unsigned c = hb[bin]; if (c >= r) break; r -= c; }
    sel[b] = (unsigned)bin;
    rem[b] = r;
  }
}

// radix pass 2 (bits[19:8] filtered by sel1) + gt_mean count
__global__ __launch_bounds__(256) void pass2_kernel(const float4* __restrict__ mag4,
    const unsigned* __restrict__ sel1, const double* __restrict__ sum,
    unsigned* __restrict__ hist2, unsigned* __restrict__ cnt_gtm)
{
  __shared__ unsigned h[4096];
  int t = threadIdx.x, b = blockIdx.x;
  for (int i = t; i < 4096; i += 256) h[i] = 0;
  __syncthreads();
  unsigned s1 = sel1[b];
  float meanf = (float)(sum[b] * (1.0/(double)NPIX));
  const int perblk = (NPIX/4)/NSPLIT;
  const float4* p = mag4 + (size_t)b*(NPIX/4) + (size_t)blockIdx.y*perblk;
  unsigned lc = 0;
  for (int i = t; i < perblk; i += 256){
    float4 v = p[i];
    float a[4] = {v.x, v.y, v.z, v.w};
    #pragma unroll
    for (int q = 0; q < 4; ++q){
      unsigned bits = __float_as_uint(a[q]);
      if ((bits >> 20) == s1) atomicAdd(&h[(bits >> 8) & 0xfffu], 1u);
      lc += (a[q] > meanf) ? 1u : 0u;
    }
  }
  __shared__ unsigned rb[256];
  rb[t] = lc; __syncthreads();
  for (int o = 128; o > 0; o >>= 1){ if (t < o) rb[t] += rb[t+o]; __syncthreads(); }
  if (t == 0) atomicAdd(cnt_gtm + b, rb[0]);
  unsigned* hb = hist2 + (size_t)b*4096;
  for (int i = t; i < 4096; i += 256){
    unsigned c = h[i];
    if (c) atomicAdd(&hb[i], c);
  }
}

__global__ void scan2_kernel(const unsigned* __restrict__ hist,
                             const unsigned* __restrict__ rem1,
                             unsigned* __restrict__ sel2, unsigned* __restrict__ rem2){
  int b = blockIdx.x;
  const unsigned* hb = hist + (size_t)b*4096;
  __shared__ unsigned part[256];
  int t = threadIdx.x;
  unsigned s = 0;
  for (int i = 0; i < 16; ++i) s += hb[t*16 + i];
  part[t] = s; __syncthreads();
  if (t == 0){
    unsigned target = rem1[b], cum = 0; int seg = 0;
    for (; seg < 256; ++seg){ if (cum + part[seg] >= target) break; cum += part[seg]; }
    unsigned r = target - cum;
    int bin = seg*16;
    for (;; ++bin){ unsigned c = hb[bin]; if (c >= r) break; r -= c; }
    sel2[b] = (unsigned)bin;
    rem2[b] = r;
  }
}

// radix pass 3: bits[7:0] among values matching the 24-bit prefix
__global__ __launch_bounds__(256) void pass3_kernel(const float4* __restrict__ mag4,
    const unsigned* __restrict__ sel1, const unsigned* __restrict__ sel2,
    unsigned* __restrict__ hist3)
{
  __shared__ unsigned h[256];
  int t = threadIdx.x, b = blockIdx.x;
  h[t] = 0;
  __syncthreads();
  unsigned pref = (sel1[b] << 12) | sel2[b];
  const int perblk = (NPIX/4)/NSPLIT;
  const float4* p = mag4 + (size_t)b*(NPIX/4) + (size_t)blockIdx.y*perblk;
  for (int i = t; i < perblk; i += 256){
    float4 v = p[i];
    float a[4] = {v.x, v.y, v.z, v.w};
    #pragma unroll
    for (int q = 0; q < 4; ++q){
      unsigned bits = __float_as_uint(a[q]);
      if ((bits >> 8) == pref) atomicAdd(&h[bits & 0xffu], 1u);
    }
  }
  __syncthreads();
  unsigned c = h[t];
  if (c) atomicAdd(&hist3[(size_t)b*256 + t], c);
}

__global__ void scan3_kernel(const unsigned* __restrict__ hist,
    const unsigned* __restrict__ sel1, const unsigned* __restrict__ sel2,
    const unsigned* __restrict__ rem2, unsigned* __restrict__ medbits){
  int b = blockIdx.x;
  if (threadIdx.x != 0) return;
  const unsigned* hb = hist + (size_t)b*256;
  unsigned target = rem2[b], r = target;
  int bin = 0;
  for (;; ++bin){ unsigned c = hb[bin]; if (c >= r) break; r -= c; }
  medbits[b] = (sel1[b] << 20) | (sel2[b] << 8) | (unsigned)bin;
}

// ---------------- features ----------------
__global__ void feats_kernel(const unsigned* __restrict__ dmax, const unsigned* __restrict__ dmin,
    const double* __restrict__ sum, const double* __restrict__ sumsq, const double* __restrict__ qsum,
    const unsigned* __restrict__ cnt_half, const unsigned* __restrict__ cnt_tenth,
    const unsigned* __restrict__ cnt_gtmean, const unsigned* __restrict__ medbits,
    float* __restrict__ feats)
{
  int b = threadIdx.x;
  if (b >= BB) return;
  float maxv = __uint_as_float(dmax[b]);
  float d = maxv + 1e-8f;
  double dd = (double)d;
  double n = (double)NPIX;
  double sm = sum[b] / dd;
  double sq = sumsq[b] / (dd*dd);
  double mean = sm / n;
  double var = (sq - sm*sm/n) / (n - 1.0);
  if (var < 0.0) var = 0.0;
  float stdv = (float)sqrt(var);
  if (stdv < 1e-8f) stdv = 1e-8f;
  float mx = maxv / d;
  float mn = __uint_as_float(dmin[b]) / d;
  float gtm = (float)((double)cnt_gtmean[b] / n);
  float med = __uint_as_float(medbits[b]) / d;
  float q0 = (float)(qsum[b*4+0] / dd * (1.0/65536.0));
  float q1 = (float)(qsum[b*4+1] / dd * (1.0/65536.0));
  float q2 = (float)(qsum[b*4+2] / dd * (1.0/65536.0));
  float q3 = (float)(qsum[b*4+3] / dd * (1.0/65536.0));
  float gh = (float)((double)cnt_half[b] / n);
  float gt = (float)((double)cnt_tenth[b] / n);
  float f[12] = {(float)mean, stdv, mx, mn, gtm, med, q0, q1, q2, q3, gh, gt};
  #pragma unroll
  for (int i = 0; i < 12; ++i){
    float v = f[i];
    v = fminf(fmaxf(v, -10.f), 10.f);
    feats[b*12 + i] = v;
  }
}

// ---------------- MLP (single block) ----------------
__global__ __launch_bounds__(512) void mlp_kernel(const float* __restrict__ feats,
    const float* __restrict__ W1, const float* __restrict__ b1,
    const float* __restrict__ g1, const float* __restrict__ be1,
    const float* __restrict__ W2, const float* __restrict__ b2,
    const float* __restrict__ g2, const float* __restrict__ be2,
    const float* __restrict__ W3, const float* __restrict__ b3,
    float* __restrict__ out)
{
  __shared__ float f[BB*12];
  __shared__ float h1[BB*64];
  __shared__ float h2[BB*128];
  __shared__ float scale[128], shift[128];
  int t = threadIdx.x;
  const int nt = 512;
  for (int i = t; i < BB*12; i += nt) f[i] = feats[i];
  __syncthreads();
  for (int i = t; i < BB*64; i += nt){
    int r = i >> 6, c = i & 63;
    float acc = b1[c];
    #pragma unroll
    for (int k = 0; k < 12; ++k) acc += f[r*12 + k] * W1[k*64 + c];
    h1[i] = acc;
  }
  __syncthreads();
  if (t < 64){
    float mu = 0.f;
    for (int r = 0; r < BB; ++r) mu += h1[r*64 + t];
    mu *= (1.f/BB);
    float var = 0.f;
    for (int r = 0; r < BB; ++r){ float dd = h1[r*64 + t] - mu; var += dd*dd; }
    var *= (1.f/BB);
    float sc = g1[t] / sqrtf(var + 1e-5f);
    scale[t] = sc; shift[t] = be1[t] - mu*sc;
  }
  __syncthreads();
  for (int i = t; i < BB*64; i += nt){
    int c = i & 63;
    float v = h1[i]*scale[c] + shift[c];
    h1[i] = v > 0.f ? v : 0.f;
  }
  __syncthreads();
  for (int i = t; i < BB*128; i += nt){
    int r = i >> 7, c = i & 127;
    float acc = b2[c];
    for (int k = 0; k < 64; ++k) acc += h1[r*64 + k] * W2[k*128 + c];
    h2[i] = acc;
  }
  __syncthreads();
  if (t < 128){
    float mu = 0.f;
    for (int r = 0; r < BB; ++r) mu += h2[r*128 + t];
    mu *= (1.f/BB);
    float var = 0.f;
    for (int r = 0; r < BB; ++r){ float dd = h2[r*128 + t] - mu; var += dd*dd; }
    var *= (1.f/BB);
    float sc = g2[t] / sqrtf(var + 1e-5f);
    scale[t] = sc; shift[t] = be2[t] - mu*sc;
  }
  __syncthreads();
  for (int i = t; i < BB*128; i += nt){
    int c = i & 127;
    float v = h2[i]*scale[c] + shift[c];
    h2[i] = v > 0.f ? v : 0.f;
  }
  __syncthreads();
  for (int i = t; i < BB*512; i += nt){
    int r = i >> 9, c = i & 511;
    float acc = b3[c];
    for (int k = 0; k < 128; ++k) acc += h2[r*128 + k] * W3[k*512 + c];
    out[i] = acc;
  }
}

// ---------------- launch ----------------
extern "C" void kernel_launch(void* const* d_in, const int* in_sizes, int n_in,
                              void* d_out, int out_size, void* d_ws, size_t ws_size,
                              hipStream_t stream) {
  (void)in_sizes; (void)n_in; (void)out_size; (void)ws_size;
  const float* x   = (const float*)d_in[0];
  const float* W1  = (const float*)d_in[1];
  const float* b1  = (const float*)d_in[2];
  const float* g1  = (const float*)d_in[3];
  const float* be1 = (const float*)d_in[4];
  const float* W2  = (const float*)d_in[5];
  const float* b2  = (const float*)d_in[6];
  const float* g2  = (const float*)d_in[7];
  const float* be2 = (const float*)d_in[8];
  const float* W3  = (const float*)d_in[9];
  const float* b3  = (const float*)d_in[10];
  float* out = (float*)d_out;

  char* ws = (char*)d_ws;
  // [0,128MB) complex row-FFT buffer (reused for radix histograms after col FFT)
  // [128MB,192MB) shifted raw magnitude
  // [192MB,+8KB) scalars
  float2* bufc = (float2*)ws;
  float* mag = (float*)(ws + 134217728);
  char* sc = ws + 201326592;
  unsigned* dmax      = (unsigned*)(sc + 0);
  unsigned* dmin      = (unsigned*)(sc + 256);
  double*   sum       = (double*)(sc + 512);
  double*   sumsq     = (double*)(sc + 1024);
  double*   qsum      = (double*)(sc + 1536);
  unsigned* cnt_half  = (unsigned*)(sc + 3584);
  unsigned* cnt_tenth = (unsigned*)(sc + 3840);
  unsigned* cnt_gtm   = (unsigned*)(sc + 4096);
  unsigned* sel1      = (unsigned*)(sc + 4352);
  unsigned* rem1      = (unsigned*)(sc + 4608);
  unsigned* sel2      = (unsigned*)(sc + 4864);
  unsigned* rem2      = (unsigned*)(sc + 5120);
  unsigned* medbits   = (unsigned*)(sc + 5376);
  float*    feats     = (float*)(sc + 5632);
  unsigned* hist1     = (unsigned*)ws;                      // 64*2048*4 = 512 KB
  unsigned* hist2     = (unsigned*)(ws + 524288);           // 64*4096*4 = 1 MB
  unsigned* hist3     = (unsigned*)(ws + 1572864);          // 64*256*4 = 64 KB

  hipMemsetAsync(sc, 0, 8192, stream);
  hipMemsetAsync(dmin, 0xFF, 256, stream);

  row_fft_kernel<<<BB*HH, 256, 0, stream>>>(x, bufc);
  col_fft_kernel<<<BB*WW, 256, 0, stream>>>(bufc, mag, dmax);

  // bufc dead from here; its space holds the radix histograms
  hipMemsetAsync(ws, 0, 1638400, stream);

  pass1_kernel<<<dim3(BB, NSPLIT), 256, 0, stream>>>((const float4*)mag, dmax,
      sum, sumsq, qsum, dmin, cnt_half, cnt_tenth, hist1);
  scan1_kernel<<<BB, 256, 0, stream>>>(hist1, sel1, rem1);
  pass2_kernel<<<dim3(BB, NSPLIT), 256, 0, stream>>>((const float4*)mag, sel1, sum, hist2, cnt_gtm);
  scan2_kernel<<<BB, 256, 0, stream>>>(hist2, rem1, sel2, rem2);
  pass3_kernel<<<dim3(BB, NSPLIT), 256, 0, stream>>>((const float4*)mag, sel1, sel2, hist3);
  scan3_kernel<<<BB, 64, 0, stream>>>(hist3, sel1, sel2, rem2, medbits);

  feats_kernel<<<1, 64, 0, stream>>>(dmax, dmin, sum, sumsq, qsum, cnt_half, cnt_tenth, cnt_gtm, medbits, feats);
  mlp_kernel<<<1, 512, 0, stream>>>(feats, W1, b1, g1, be1, W2, b2, g2, be2, W3, b3, out);
}

// Round 3
// 612.564 us; speedup vs baseline: 2.2924x; 1.4920x over previous
//
#include <hip/hip_runtime.h>
#include <math.h>

#ifndef M_PI
#define M_PI 3.14159265358979323846
#endif

#define BB 64
#define HH 512
#define WW 512
#define NPIX (HH*WW)        // 262144
#define MED_K 131072u       // 1-indexed rank of (n-1)//2
#define WS 260              // mag row stride (floats), cols 0..256 valid

__device__ __forceinline__ float2 cmulf(float2 a, float2 b){
  return make_float2(a.x*b.x - a.y*b.y, a.x*b.y + a.y*b.x);
}
__device__ __forceinline__ unsigned rev9(unsigned v){ return __brev(v) >> 23; }

__device__ __forceinline__ double wred_add(double v){
  #pragma unroll
  for (int o = 32; o > 0; o >>= 1) v += __shfl_down(v, o, 64);
  return v;
}
__device__ __forceinline__ float wred_min(float v){
  #pragma unroll
  for (int o = 32; o > 0; o >>= 1) v = fminf(v, __shfl_down(v, o, 64));
  return v;
}
__device__ __forceinline__ float wred_max(float v){
  #pragma unroll
  for (int o = 32; o > 0; o >>= 1) v = fmaxf(v, __shfl_down(v, o, 64));
  return v;
}
__device__ __forceinline__ unsigned wred_addu(unsigned v){
  #pragma unroll
  for (int o = 32; o > 0; o >>= 1) v += __shfl_down(v, o, 64);
  return v;
}

// ---------------- row FFT (writes only cols 0..256 of spectrum) ----------------
__global__ __launch_bounds__(256) void row_fft_kernel(const float* __restrict__ x,
                                                      float2* __restrict__ out){
  __shared__ float2 s[512];
  __shared__ float2 tw[256];
  int t = threadIdx.x;
  {
    double a = -2.0 * M_PI * (double)t / 512.0;
    tw[t] = make_float2((float)cos(a), (float)sin(a));
  }
  int row = blockIdx.x;               // b*512 + h
  int b = row >> 9;
  const float* rp = x + (size_t)b*3*NPIX + (size_t)(row & 511)*WW;
  const float* gp = rp + NPIX;
  const float* bp = rp + 2*NPIX;
  for (int k = t; k < 512; k += 256){
    float g = 0.299f*rp[k] + 0.587f*gp[k] + 0.114f*bp[k];
    s[rev9((unsigned)k)] = make_float2(g, 0.f);
  }
  __syncthreads();
  #pragma unroll
  for (int st = 1; st <= 9; ++st){
    int half = 1 << (st-1);
    int k = t & (half - 1);
    int i1 = ((t >> (st-1)) << st) + k;
    int i2 = i1 + half;
    float2 w = tw[k << (9 - st)];
    float2 u = s[i1];
    float2 v = cmulf(w, s[i2]);
    s[i1] = make_float2(u.x + v.x, u.y + v.y);
    s[i2] = make_float2(u.x - v.x, u.y - v.y);
    __syncthreads();
  }
  float2* o = out + (size_t)row*WW;
  for (int k = t; k < 512; k += 256)
    if (k <= 256) o[k] = s[k];        // Hermitian: cols 257..511 are mirrors, never read
}

// ---------------- col FFT, 16-column tiles, fused stats + hist1 ----------------
// grid: BB*17 blocks (tiles j0=0,16,...,256), 512 threads.
// Computes mag for j=0..256 only; stats weighted (w=2 for j=1..255).
__global__ __launch_bounds__(512) void col_fft_kernel(const float2* __restrict__ in,
    float* __restrict__ magc,
    unsigned* __restrict__ dmax, unsigned* __restrict__ dmin,
    double* __restrict__ sum, double* __restrict__ sumsq, double* __restrict__ qsum,
    unsigned* __restrict__ hist1)
{
  __shared__ float2 s[512*16];
  __shared__ float2 tw[256];
  __shared__ unsigned h[2048];
  __shared__ double bufd[6][8];
  __shared__ float buff[2][8];
  int t = threadIdx.x;
  if (t < 256){
    double a = -2.0 * M_PI * (double)t / 512.0;
    tw[t] = make_float2((float)cos(a), (float)sin(a));
  }
  for (int i = t; i < 2048; i += 512) h[i] = 0;
  int b = blockIdx.x / 17;
  int j0 = (blockIdx.x % 17) << 4;
  const float2* base = in + (size_t)b*NPIX;
  for (int idx = t; idx < 512*16; idx += 512){
    int e = idx >> 4, c = idx & 15;
    int j = j0 + c;
    float2 v = (j <= 256) ? base[(size_t)e*WW + j] : make_float2(0.f, 0.f);
    s[(int)rev9((unsigned)e)*16 + c] = v;
  }
  __syncthreads();
  #pragma unroll
  for (int st = 1; st <= 9; ++st){
    int half = 1 << (st-1);
    #pragma unroll
    for (int qq = 0; qq < 8; ++qq){
      int tt = t + (qq << 9);
      int c = tt & 15;
      int kk = tt >> 4;                 // 0..255
      int k = kk & (half - 1);
      int i1 = ((kk >> (st-1)) << st) + k;
      int i2 = i1 + half;
      float2 w = tw[k << (9 - st)];
      float2 u = s[i1*16 + c];
      float2 v = cmulf(w, s[i2*16 + c]);
      s[i1*16 + c] = make_float2(u.x + v.x, u.y + v.y);
      s[i2*16 + c] = make_float2(u.x - v.x, u.y - v.y);
    }
    __syncthreads();
  }
  // store mag + fused stats
  double lsum=0.0, lsq=0.0, lq0=0.0, lq1=0.0, lq2=0.0, lq3=0.0;
  float lmn = 3.4e38f, lmx = 0.f;
  float* mo = magc + (size_t)b*(512*WS);
  for (int idx = t; idx < 512*16; idx += 512){
    int e = idx >> 4, c = idx & 15;
    int j = j0 + c;
    if (j > 256) continue;
    float2 v = s[e*16 + c];
    float m = sqrtf(v.x*v.x + v.y*v.y) + 1e-8f;
    int si = (e + 256) & 511;           // fftshift along H
    mo[(size_t)si*WS + j] = m;
    unsigned w = (j == 0 || j == 256) ? 1u : 2u;
    double md = (double)m;
    double wm = (w == 2u) ? md + md : md;
    lsum += wm;
    lsq  += wm * md;
    lmn = fminf(lmn, m); lmx = fmaxf(lmx, m);
    atomicAdd(&h[__float_as_uint(m) >> 20], w);
    int qa = si >> 7;
    lq0 += (qa==0)?md:0.0; lq1 += (qa==1)?md:0.0; lq2 += (qa==2)?md:0.0; lq3 += (qa==3)?md:0.0;
    if (w == 2u){
      int qb = ((512 - si) & 511) >> 7; // mirror row's quadrant
      lq0 += (qb==0)?md:0.0; lq1 += (qb==1)?md:0.0; lq2 += (qb==2)?md:0.0; lq3 += (qb==3)?md:0.0;
    }
  }
  int lane = t & 63, wv = t >> 6;
  double r0 = wred_add(lsum), r1 = wred_add(lsq);
  double r2 = wred_add(lq0), r3 = wred_add(lq1), r4 = wred_add(lq2), r5 = wred_add(lq3);
  float fmn = wred_min(lmn), fmx = wred_max(lmx);
  if (lane == 0){
    bufd[0][wv]=r0; bufd[1][wv]=r1; bufd[2][wv]=r2;
    bufd[3][wv]=r3; bufd[4][wv]=r4; bufd[5][wv]=r5;
    buff[0][wv]=fmn; buff[1][wv]=fmx;
  }
  __syncthreads();
  if (t == 0){
    double s0=0,s1=0,s2=0,s3=0,s4=0,s5=0; float mn=3.4e38f, mx=0.f;
    for (int i = 0; i < 8; ++i){
      s0+=bufd[0][i]; s1+=bufd[1][i]; s2+=bufd[2][i];
      s3+=bufd[3][i]; s4+=bufd[4][i]; s5+=bufd[5][i];
      mn=fminf(mn,buff[0][i]); mx=fmaxf(mx,buff[1][i]);
    }
    atomicAdd(sum + b, s0);
    atomicAdd(sumsq + b, s1);
    atomicAdd(qsum + b*4 + 0, s2);
    atomicAdd(qsum + b*4 + 1, s3);
    atomicAdd(qsum + b*4 + 2, s4);
    atomicAdd(qsum + b*4 + 3, s5);
    atomicMin(dmin + b, __float_as_uint(mn));
    atomicMax(dmax + b, __float_as_uint(mx));
  }
  // merge hist1
  unsigned* hb = hist1 + (size_t)b*2048;
  for (int i = t; i < 2048; i += 512){
    unsigned c = h[i];
    if (c) atomicAdd(&hb[i], c);
  }
}

__global__ void scan1_kernel(const unsigned* __restrict__ hist,
                             unsigned* __restrict__ sel, unsigned* __restrict__ rem){
  int b = blockIdx.x;
  const unsigned* hb = hist + (size_t)b*2048;
  __shared__ unsigned part[256];
  int t = threadIdx.x;
  unsigned s = 0;
  for (int i = 0; i < 8; ++i) s += hb[t*8 + i];
  part[t] = s; __syncthreads();
  if (t == 0){
    unsigned target = MED_K, cum = 0; int seg = 0;
    for (; seg < 256; ++seg){ if (cum + part[seg] >= target) break; cum += part[seg]; }
    unsigned r = target - cum;
    int bin = seg*8;
    for (;; ++bin){ unsigned c = hb[bin]; if (c >= r) break; r -= c; }
    sel[b] = (unsigned)bin;
    rem[b] = r;
  }
}

// pass2: hist of bits[19:6] among sel1-prefix matches + gt_mean/cnt_half/cnt_tenth
// grid (BB, 16): each block handles 32 rows of the compact mag plane.
__global__ __launch_bounds__(256) void pass2_kernel(const float4* __restrict__ magc4,
    const unsigned* __restrict__ sel1, const double* __restrict__ sum,
    const unsigned* __restrict__ dmax,
    unsigned* __restrict__ hist2, unsigned* __restrict__ cnt_gtm,
    unsigned* __restrict__ cnt_half, unsigned* __restrict__ cnt_tenth)
{
  __shared__ unsigned h[16384];
  __shared__ unsigned rb[3][8];
  int t = threadIdx.x, b = blockIdx.x;
  for (int i = t; i < 16384; i += 256) h[i] = 0;
  __syncthreads();
  unsigned s1 = sel1[b];
  float meanf = (float)(sum[b] / (double)NPIX);
  float d = __uint_as_float(dmax[b]) + 1e-8f;
  float th = 0.5f*d, tl = 0.1f*d;
  const float4* p = magc4 + (size_t)b*(512*(WS/4)) + (size_t)blockIdx.y*32*(WS/4);
  unsigned lgm = 0, lh = 0, lt = 0;
  for (int idx = t; idx < 32*(WS/4); idx += 256){
    float4 v = p[idx];
    int k = idx % (WS/4);
    int jc0 = k*4;
    float a[4] = {v.x, v.y, v.z, v.w};
    #pragma unroll
    for (int q = 0; q < 4; ++q){
      int jc = jc0 + q;
      if (jc > 256) continue;
      unsigned w = (jc == 0 || jc == 256) ? 1u : 2u;
      float m = a[q];
      unsigned bits = __float_as_uint(m);
      if ((bits >> 20) == s1) atomicAdd(&h[(bits >> 6) & 0x3fffu], w);
      lgm += (m > meanf) ? w : 0u;
      lh  += (m > th) ? w : 0u;
      lt  += (m > tl) ? w : 0u;
    }
  }
  int lane = t & 63, wv = t >> 6;
  unsigned g0 = wred_addu(lgm), g1 = wred_addu(lh), g2 = wred_addu(lt);
  if (lane == 0){ rb[0][wv]=g0; rb[1][wv]=g1; rb[2][wv]=g2; }
  __syncthreads();
  if (t == 0){
    unsigned a0=0,a1=0,a2=0;
    for (int i = 0; i < 4; ++i){ a0+=rb[0][i]; a1+=rb[1][i]; a2+=rb[2][i]; }
    atomicAdd(cnt_gtm + b, a0);
    atomicAdd(cnt_half + b, a1);
    atomicAdd(cnt_tenth + b, a2);
  }
  unsigned* hb = hist2 + (size_t)b*16384;
  for (int i = t; i < 16384; i += 256){
    unsigned c = h[i];
    if (c) atomicAdd(&hb[i], c);
  }
}

__global__ void scan2_kernel(const unsigned* __restrict__ hist,
    const unsigned* __restrict__ sel1, const unsigned* __restrict__ rem1,
    unsigned* __restrict__ medbits){
  int b = blockIdx.x;
  const unsigned* hb = hist + (size_t)b*16384;
  __shared__ unsigned part[256];
  int t = threadIdx.x;
  unsigned s = 0;
  for (int i = 0; i < 64; ++i) s += hb[t*64 + i];
  part[t] = s; __syncthreads();
  if (t == 0){
    unsigned target = rem1[b], cum = 0; int seg = 0;
    for (; seg < 256; ++seg){ if (cum + part[seg] >= target) break; cum += part[seg]; }
    unsigned r = target - cum;
    int bin = seg*64;
    for (;; ++bin){ unsigned c = hb[bin]; if (c >= r) break; r -= c; }
    medbits[b] = (sel1[b] << 20) | ((unsigned)bin << 6) | 32u;  // low 6 bits ~ midpoint
  }
}

// ---------------- features ----------------
__global__ void feats_kernel(const unsigned* __restrict__ dmax, const unsigned* __restrict__ dmin,
    const double* __restrict__ sum, const double* __restrict__ sumsq, const double* __restrict__ qsum,
    const unsigned* __restrict__ cnt_half, const unsigned* __restrict__ cnt_tenth,
    const unsigned* __restrict__ cnt_gtmean, const unsigned* __restrict__ medbits,
    float* __restrict__ feats)
{
  int b = threadIdx.x;
  if (b >= BB) return;
  float maxv = __uint_as_float(dmax[b]);
  float d = maxv + 1e-8f;
  double dd = (double)d;
  double n = (double)NPIX;
  double sm = sum[b] / dd;
  double sq = sumsq[b] / (dd*dd);
  double mean = sm / n;
  double var = (sq - sm*sm/n) / (n - 1.0);
  if (var < 0.0) var = 0.0;
  float stdv = (float)sqrt(var);
  if (stdv < 1e-8f) stdv = 1e-8f;
  float mx = maxv / d;
  float mn = __uint_as_float(dmin[b]) / d;
  float gtm = (float)((double)cnt_gtmean[b] / n);
  float med = __uint_as_float(medbits[b]) / d;
  float q0 = (float)(qsum[b*4+0] / dd * (1.0/65536.0));
  float q1 = (float)(qsum[b*4+1] / dd * (1.0/65536.0));
  float q2 = (float)(qsum[b*4+2] / dd * (1.0/65536.0));
  float q3 = (float)(qsum[b*4+3] / dd * (1.0/65536.0));
  float gh = (float)((double)cnt_half[b] / n);
  float gt = (float)((double)cnt_tenth[b] / n);
  float f[12] = {(float)mean, stdv, mx, mn, gtm, med, q0, q1, q2, q3, gh, gt};
  #pragma unroll
  for (int i = 0; i < 12; ++i){
    float v = f[i];
    v = fminf(fmaxf(v, -10.f), 10.f);
    feats[b*12 + i] = v;
  }
}

// ---------------- MLP (single block) ----------------
__global__ __launch_bounds__(512) void mlp_kernel(const float* __restrict__ feats,
    const float* __restrict__ W1, const float* __restrict__ b1,
    const float* __restrict__ g1, const float* __restrict__ be1,
    const float* __restrict__ W2, const float* __restrict__ b2,
    const float* __restrict__ g2, const float* __restrict__ be2,
    const float* __restrict__ W3, const float* __restrict__ b3,
    float* __restrict__ out)
{
  __shared__ float f[BB*12];
  __shared__ float h1[BB*64];
  __shared__ float h2[BB*128];
  __shared__ float scale[128], shift[128];
  int t = threadIdx.x;
  const int nt = 512;
  for (int i = t; i < BB*12; i += nt) f[i] = feats[i];
  __syncthreads();
  for (int i = t; i < BB*64; i += nt){
    int r = i >> 6, c = i & 63;
    float acc = b1[c];
    #pragma unroll
    for (int k = 0; k < 12; ++k) acc += f[r*12 + k] * W1[k*64 + c];
    h1[i] = acc;
  }
  __syncthreads();
  if (t < 64){
    float mu = 0.f;
    for (int r = 0; r < BB; ++r) mu += h1[r*64 + t];
    mu *= (1.f/BB);
    float var = 0.f;
    for (int r = 0; r < BB; ++r){ float dd = h1[r*64 + t] - mu; var += dd*dd; }
    var *= (1.f/BB);
    float sc = g1[t] / sqrtf(var + 1e-5f);
    scale[t] = sc; shift[t] = be1[t] - mu*sc;
  }
  __syncthreads();
  for (int i = t; i < BB*64; i += nt){
    int c = i & 63;
    float v = h1[i]*scale[c] + shift[c];
    h1[i] = v > 0.f ? v : 0.f;
  }
  __syncthreads();
  for (int i = t; i < BB*128; i += nt){
    int r = i >> 7, c = i & 127;
    float acc = b2[c];
    for (int k = 0; k < 64; ++k) acc += h1[r*64 + k] * W2[k*128 + c];
    h2[i] = acc;
  }
  __syncthreads();
  if (t < 128){
    float mu = 0.f;
    for (int r = 0; r < BB; ++r) mu += h2[r*128 + t];
    mu *= (1.f/BB);
    float var = 0.f;
    for (int r = 0; r < BB; ++r){ float dd = h2[r*128 + t] - mu; var += dd*dd; }
    var *= (1.f/BB);
    float sc = g2[t] / sqrtf(var + 1e-5f);
    scale[t] = sc; shift[t] = be2[t] - mu*sc;
  }
  __syncthreads();
  for (int i = t; i < BB*128; i += nt){
    int c = i & 127;
    float v = h2[i]*scale[c] + shift[c];
    h2[i] = v > 0.f ? v : 0.f;
  }
  __syncthreads();
  for (int i = t; i < BB*512; i += nt){
    int r = i >> 9, c = i & 511;
    float acc = b3[c];
    for (int k = 0; k < 128; ++k) acc += h2[r*128 + k] * W3[k*512 + c];
    out[i] = acc;
  }
}

// ---------------- launch ----------------
extern "C" void kernel_launch(void* const* d_in, const int* in_sizes, int n_in,
                              void* d_out, int out_size, void* d_ws, size_t ws_size,
                              hipStream_t stream) {
  (void)in_sizes; (void)n_in; (void)out_size; (void)ws_size;
  const float* x   = (const float*)d_in[0];
  const float* W1  = (const float*)d_in[1];
  const float* b1  = (const float*)d_in[2];
  const float* g1  = (const float*)d_in[3];
  const float* be1 = (const float*)d_in[4];
  const float* W2  = (const float*)d_in[5];
  const float* b2  = (const float*)d_in[6];
  const float* g2  = (const float*)d_in[7];
  const float* be2 = (const float*)d_in[8];
  const float* W3  = (const float*)d_in[9];
  const float* b3  = (const float*)d_in[10];
  float* out = (float*)d_out;

  char* ws = (char*)d_ws;
  // [0,128M)            bufc: row-FFT spectrum, cols 0..256 used (stride 512)
  // [128M, +34,078,720) magc: compact shifted magnitude, 512 x 260 per batch
  // then hist1 (512 KB), hist2 (4 MB), scalars (8 KB) — total < 168 MB
  float2* bufc = (float2*)ws;
  float*  magc = (float*)(ws + 134217728);
  unsigned* hist1 = (unsigned*)(ws + 134217728 + 34078720);       // 168,296,448
  unsigned* hist2 = (unsigned*)(ws + 168296448 + 524288);         // 168,820,736
  char* sc = ws + 168820736 + 4194304;                            // 173,015,040
  unsigned* dmax      = (unsigned*)(sc + 0);
  unsigned* dmin      = (unsigned*)(sc + 256);
  double*   sum       = (double*)(sc + 512);
  double*   sumsq     = (double*)(sc + 1024);
  double*   qsum      = (double*)(sc + 1536);
  unsigned* cnt_half  = (unsigned*)(sc + 3584);
  unsigned* cnt_tenth = (unsigned*)(sc + 3840);
  unsigned* cnt_gtm   = (unsigned*)(sc + 4096);
  unsigned* sel1      = (unsigned*)(sc + 4352);
  unsigned* rem1      = (unsigned*)(sc + 4608);
  unsigned* medbits   = (unsigned*)(sc + 4864);
  float*    feats     = (float*)(sc + 5120);

  hipMemsetAsync(hist1, 0, 524288 + 4194304, stream);   // hist1+hist2 contiguous
  hipMemsetAsync(sc, 0, 8192, stream);
  hipMemsetAsync(dmin, 0xFF, 256, stream);

  row_fft_kernel<<<BB*HH, 256, 0, stream>>>(x, bufc);
  col_fft_kernel<<<BB*17, 512, 0, stream>>>(bufc, magc, dmax, dmin, sum, sumsq, qsum, hist1);
  scan1_kernel<<<BB, 256, 0, stream>>>(hist1, sel1, rem1);
  pass2_kernel<<<dim3(BB, 16), 256, 0, stream>>>((const float4*)magc, sel1, sum, dmax,
      hist2, cnt_gtm, cnt_half, cnt_tenth);
  scan2_kernel<<<BB, 256, 0, stream>>>(hist2, sel1, rem1, medbits);
  feats_kernel<<<1, 64, 0, stream>>>(dmax, dmin, sum, sumsq, qsum, cnt_half, cnt_tenth, cnt_gtm, medbits, feats);
  mlp_kernel<<<1, 512, 0, stream>>>(feats, W1, b1, g1, be1, W2, b2, g2, be2, W3, b3, out);
}

// Round 4
// 470.362 us; speedup vs baseline: 2.9854x; 1.3023x over previous
//
#include <hip/hip_runtime.h>
#include <math.h>

#ifndef M_PI
#define M_PI 3.14159265358979323846
#endif

#define BB 64
#define HH 512
#define WW 512
#define NPIX (HH*WW)        // 262144
#define MED_K 131072u       // 1-indexed rank of (n-1)//2
#define WS 260              // mag row stride (floats), cols 0..256 valid
#define PADI(i) ((i) + ((i) >> 5))

__device__ __forceinline__ float2 cmulf(float2 a, float2 b){
  return make_float2(a.x*b.x - a.y*b.y, a.x*b.y + a.y*b.x);
}
__device__ __forceinline__ unsigned rev9(unsigned v){ return __brev(v) >> 23; }

__device__ __forceinline__ double wred_add(double v){
  #pragma unroll
  for (int o = 32; o > 0; o >>= 1) v += __shfl_down(v, o, 64);
  return v;
}
__device__ __forceinline__ float wred_min(float v){
  #pragma unroll
  for (int o = 32; o > 0; o >>= 1) v = fminf(v, __shfl_down(v, o, 64));
  return v;
}
__device__ __forceinline__ float wred_max(float v){
  #pragma unroll
  for (int o = 32; o > 0; o >>= 1) v = fmaxf(v, __shfl_down(v, o, 64));
  return v;
}
__device__ __forceinline__ unsigned wred_addu(unsigned v){
  #pragma unroll
  for (int o = 32; o > 0; o >>= 1) v += __shfl_down(v, o, 64);
  return v;
}
__device__ __forceinline__ float wred_add_all(float v){
  #pragma unroll
  for (int o = 32; o > 0; o >>= 1) v += __shfl_xor(v, o, 64);
  return v;
}

// ---------------- row FFT (padded SoA LDS; writes only cols 0..256) ----------------
__global__ __launch_bounds__(256) void row_fft_kernel(const float* __restrict__ x,
                                                      float2* __restrict__ out){
  __shared__ float sre[528], sim[528];
  __shared__ float2 tw[256];
  int t = threadIdx.x;
  {
    double a = -2.0 * M_PI * (double)t / 512.0;
    tw[t] = make_float2((float)cos(a), (float)sin(a));
  }
  int row = blockIdx.x;               // b*512 + h
  int b = row >> 9;
  const float* rp = x + (size_t)b*3*NPIX + (size_t)(row & 511)*WW;
  const float* gp = rp + NPIX;
  const float* bp = rp + 2*NPIX;
  for (int k = t; k < 512; k += 256){
    float g = 0.299f*rp[k] + 0.587f*gp[k] + 0.114f*bp[k];
    int ri = (int)rev9((unsigned)k);
    sre[PADI(ri)] = g; sim[PADI(ri)] = 0.f;
  }
  __syncthreads();
  #pragma unroll
  for (int st = 1; st <= 9; ++st){
    int half = 1 << (st-1);
    int k = t & (half - 1);
    int i1 = ((t >> (st-1)) << st) + k;
    int i2 = i1 + half;
    int p1 = PADI(i1), p2 = PADI(i2);
    float2 w = tw[k << (9 - st)];
    float2 u = make_float2(sre[p1], sim[p1]);
    float2 raw = make_float2(sre[p2], sim[p2]);
    float2 v = cmulf(w, raw);
    sre[p1] = u.x + v.x; sim[p1] = u.y + v.y;
    sre[p2] = u.x - v.x; sim[p2] = u.y - v.y;
    __syncthreads();
  }
  float2* o = out + (size_t)row*WW;
  for (int k = t; k < 512; k += 256)
    if (k <= 256){ int p = PADI(k); o[k] = make_float2(sre[p], sim[p]); }
}

// ---------------- col FFT, 16-column tiles, fused stats + hist1 ----------------
__global__ __launch_bounds__(512) void col_fft_kernel(const float2* __restrict__ in,
    float* __restrict__ magc,
    unsigned* __restrict__ dmax, unsigned* __restrict__ dmin,
    double* __restrict__ sum, double* __restrict__ sumsq, double* __restrict__ qsum,
    unsigned* __restrict__ hist1)
{
  __shared__ float2 s[512*16];
  __shared__ float2 tw[256];
  __shared__ unsigned h[2048];
  __shared__ double bufd[6][8];
  __shared__ float buff[2][8];
  int t = threadIdx.x;
  if (t < 256){
    double a = -2.0 * M_PI * (double)t / 512.0;
    tw[t] = make_float2((float)cos(a), (float)sin(a));
  }
  for (int i = t; i < 2048; i += 512) h[i] = 0;
  int b = blockIdx.x / 17;
  int j0 = (blockIdx.x % 17) << 4;
  const float2* base = in + (size_t)b*NPIX;
  for (int idx = t; idx < 512*16; idx += 512){
    int e = idx >> 4, c = idx & 15;
    int j = j0 + c;
    float2 v = (j <= 256) ? base[(size_t)e*WW + j] : make_float2(0.f, 0.f);
    s[(int)rev9((unsigned)e)*16 + c] = v;
  }
  __syncthreads();
  #pragma unroll
  for (int st = 1; st <= 9; ++st){
    int half = 1 << (st-1);
    #pragma unroll
    for (int qq = 0; qq < 8; ++qq){
      int tt = t + (qq << 9);
      int c = tt & 15;
      int kk = tt >> 4;
      int k = kk & (half - 1);
      int i1 = ((kk >> (st-1)) << st) + k;
      int i2 = i1 + half;
      float2 w = tw[k << (9 - st)];
      float2 u = s[i1*16 + c];
      float2 v = cmulf(w, s[i2*16 + c]);
      s[i1*16 + c] = make_float2(u.x + v.x, u.y + v.y);
      s[i2*16 + c] = make_float2(u.x - v.x, u.y - v.y);
    }
    __syncthreads();
  }
  double lsum=0.0, lsq=0.0, lq0=0.0, lq1=0.0, lq2=0.0, lq3=0.0;
  float lmn = 3.4e38f, lmx = 0.f;
  float* mo = magc + (size_t)b*(512*WS);
  for (int idx = t; idx < 512*16; idx += 512){
    int e = idx >> 4, c = idx & 15;
    int j = j0 + c;
    if (j > 256) continue;
    float2 v = s[e*16 + c];
    float m = sqrtf(v.x*v.x + v.y*v.y) + 1e-8f;
    int si = (e + 256) & 511;
    mo[(size_t)si*WS + j] = m;
    unsigned w = (j == 0 || j == 256) ? 1u : 2u;
    double md = (double)m;
    double wm = (w == 2u) ? md + md : md;
    lsum += wm;
    lsq  += wm * md;
    lmn = fminf(lmn, m); lmx = fmaxf(lmx, m);
    atomicAdd(&h[__float_as_uint(m) >> 20], w);
    int qa = si >> 7;
    lq0 += (qa==0)?md:0.0; lq1 += (qa==1)?md:0.0; lq2 += (qa==2)?md:0.0; lq3 += (qa==3)?md:0.0;
    if (w == 2u){
      int qb = ((512 - si) & 511) >> 7;
      lq0 += (qb==0)?md:0.0; lq1 += (qb==1)?md:0.0; lq2 += (qb==2)?md:0.0; lq3 += (qb==3)?md:0.0;
    }
  }
  int lane = t & 63, wv = t >> 6;
  double r0 = wred_add(lsum), r1 = wred_add(lsq);
  double r2 = wred_add(lq0), r3 = wred_add(lq1), r4 = wred_add(lq2), r5 = wred_add(lq3);
  float fmn = wred_min(lmn), fmx = wred_max(lmx);
  if (lane == 0){
    bufd[0][wv]=r0; bufd[1][wv]=r1; bufd[2][wv]=r2;
    bufd[3][wv]=r3; bufd[4][wv]=r4; bufd[5][wv]=r5;
    buff[0][wv]=fmn; buff[1][wv]=fmx;
  }
  __syncthreads();
  if (t == 0){
    double s0=0,s1=0,s2=0,s3=0,s4=0,s5=0; float mn=3.4e38f, mx=0.f;
    for (int i = 0; i < 8; ++i){
      s0+=bufd[0][i]; s1+=bufd[1][i]; s2+=bufd[2][i];
      s3+=bufd[3][i]; s4+=bufd[4][i]; s5+=bufd[5][i];
      mn=fminf(mn,buff[0][i]); mx=fmaxf(mx,buff[1][i]);
    }
    atomicAdd(sum + b, s0);
    atomicAdd(sumsq + b, s1);
    atomicAdd(qsum + b*4 + 0, s2);
    atomicAdd(qsum + b*4 + 1, s3);
    atomicAdd(qsum + b*4 + 2, s4);
    atomicAdd(qsum + b*4 + 3, s5);
    atomicMin(dmin + b, __float_as_uint(mn));
    atomicMax(dmax + b, __float_as_uint(mx));
  }
  unsigned* hb = hist1 + (size_t)b*2048;
  for (int i = t; i < 2048; i += 512){
    unsigned c = h[i];
    if (c) atomicAdd(&hb[i], c);
  }
}

__global__ void scan1_kernel(const unsigned* __restrict__ hist,
                             unsigned* __restrict__ sel, unsigned* __restrict__ rem){
  int b = blockIdx.x;
  const unsigned* hb = hist + (size_t)b*2048;
  __shared__ unsigned part[256];
  int t = threadIdx.x;
  unsigned s = 0;
  for (int i = 0; i < 8; ++i) s += hb[t*8 + i];
  part[t] = s; __syncthreads();
  if (t == 0){
    unsigned target = MED_K, cum = 0; int seg = 0;
    for (; seg < 256; ++seg){ if (cum + part[seg] >= target) break; cum += part[seg]; }
    unsigned r = target - cum;
    int bin = seg*8;
    for (;; ++bin){ unsigned c = hb[bin]; if (c >= r) break; r -= c; }
    sel[b] = (unsigned)bin;
    rem[b] = r;
  }
}

// pass2: grid (BB, 4); each block covers 128 rows of the compact mag plane.
__global__ __launch_bounds__(256) void pass2_kernel(const float4* __restrict__ magc4,
    const unsigned* __restrict__ sel1, const double* __restrict__ sum,
    const unsigned* __restrict__ dmax,
    unsigned* __restrict__ hist2, unsigned* __restrict__ cnt_gtm,
    unsigned* __restrict__ cnt_half, unsigned* __restrict__ cnt_tenth)
{
  __shared__ unsigned h[16384];
  __shared__ unsigned rb[3][8];
  int t = threadIdx.x, b = blockIdx.x;
  for (int i = t; i < 16384; i += 256) h[i] = 0;
  __syncthreads();
  unsigned s1 = sel1[b];
  float meanf = (float)(sum[b] / (double)NPIX);
  float d = __uint_as_float(dmax[b]) + 1e-8f;
  float th = 0.5f*d, tl = 0.1f*d;
  const float4* p = magc4 + (size_t)b*(512*(WS/4)) + (size_t)blockIdx.y*128*(WS/4);
  unsigned lgm = 0, lh = 0, lt = 0;
  for (int idx = t; idx < 128*(WS/4); idx += 256){
    float4 v = p[idx];
    int k = idx % (WS/4);
    int jc0 = k*4;
    float a[4] = {v.x, v.y, v.z, v.w};
    #pragma unroll
    for (int q = 0; q < 4; ++q){
      int jc = jc0 + q;
      if (jc > 256) continue;
      unsigned w = (jc == 0 || jc == 256) ? 1u : 2u;
      float m = a[q];
      unsigned bits = __float_as_uint(m);
      if ((bits >> 20) == s1) atomicAdd(&h[(bits >> 6) & 0x3fffu], w);
      lgm += (m > meanf) ? w : 0u;
      lh  += (m > th) ? w : 0u;
      lt  += (m > tl) ? w : 0u;
    }
  }
  int lane = t & 63, wv = t >> 6;
  unsigned g0 = wred_addu(lgm), g1 = wred_addu(lh), g2 = wred_addu(lt);
  if (lane == 0){ rb[0][wv]=g0; rb[1][wv]=g1; rb[2][wv]=g2; }
  __syncthreads();
  if (t == 0){
    unsigned a0=0,a1=0,a2=0;
    for (int i = 0; i < 4; ++i){ a0+=rb[0][i]; a1+=rb[1][i]; a2+=rb[2][i]; }
    atomicAdd(cnt_gtm + b, a0);
    atomicAdd(cnt_half + b, a1);
    atomicAdd(cnt_tenth + b, a2);
  }
  unsigned* hb = hist2 + (size_t)b*16384;
  for (int i = t; i < 16384; i += 256){
    unsigned c = h[i];
    if (c) atomicAdd(&hb[i], c);
  }
}

__global__ void scan2_kernel(const unsigned* __restrict__ hist,
    const unsigned* __restrict__ sel1, const unsigned* __restrict__ rem1,
    unsigned* __restrict__ medbits){
  int b = blockIdx.x;
  const unsigned* hb = hist + (size_t)b*16384;
  __shared__ unsigned part[256];
  int t = threadIdx.x;
  unsigned s = 0;
  for (int i = 0; i < 64; ++i) s += hb[t*64 + i];
  part[t] = s; __syncthreads();
  if (t == 0){
    unsigned target = rem1[b], cum = 0; int seg = 0;
    for (; seg < 256; ++seg){ if (cum + part[seg] >= target) break; cum += part[seg]; }
    unsigned r = target - cum;
    int bin = seg*64;
    for (;; ++bin){ unsigned c = hb[bin]; if (c >= r) break; r -= c; }
    medbits[b] = (sel1[b] << 20) | ((unsigned)bin << 6) | 32u;
  }
}

// ---------------- features ----------------
__global__ void feats_kernel(const unsigned* __restrict__ dmax, const unsigned* __restrict__ dmin,
    const double* __restrict__ sum, const double* __restrict__ sumsq, const double* __restrict__ qsum,
    const unsigned* __restrict__ cnt_half, const unsigned* __restrict__ cnt_tenth,
    const unsigned* __restrict__ cnt_gtmean, const unsigned* __restrict__ medbits,
    float* __restrict__ feats)
{
  int b = threadIdx.x;
  if (b >= BB) return;
  float maxv = __uint_as_float(dmax[b]);
  float d = maxv + 1e-8f;
  double dd = (double)d;
  double n = (double)NPIX;
  double sm = sum[b] / dd;
  double sq = sumsq[b] / (dd*dd);
  double mean = sm / n;
  double var = (sq - sm*sm/n) / (n - 1.0);
  if (var < 0.0) var = 0.0;
  float stdv = (float)sqrt(var);
  if (stdv < 1e-8f) stdv = 1e-8f;
  float mx = maxv / d;
  float mn = __uint_as_float(dmin[b]) / d;
  float gtm = (float)((double)cnt_gtmean[b] / n);
  float med = __uint_as_float(medbits[b]) / d;
  float q0 = (float)(qsum[b*4+0] / dd * (1.0/65536.0));
  float q1 = (float)(qsum[b*4+1] / dd * (1.0/65536.0));
  float q2 = (float)(qsum[b*4+2] / dd * (1.0/65536.0));
  float q3 = (float)(qsum[b*4+3] / dd * (1.0/65536.0));
  float gh = (float)((double)cnt_half[b] / n);
  float gt = (float)((double)cnt_tenth[b] / n);
  float f[12] = {(float)mean, stdv, mx, mn, gtm, med, q0, q1, q2, q3, gh, gt};
  #pragma unroll
  for (int i = 0; i < 12; ++i){
    float v = f[i];
    v = fminf(fmaxf(v, -10.f), 10.f);
    feats[b*12 + i] = v;
  }
}

// ---------------- MLP: column-parallel, BN per-column in one wave ----------------
// mlp1: 64 blocks x 64 thr; block = column c of h1; lane = row r.
__global__ __launch_bounds__(64) void mlp1_kernel(const float* __restrict__ feats,
    const float* __restrict__ W1, const float* __restrict__ b1,
    const float* __restrict__ g1, const float* __restrict__ be1,
    float* __restrict__ h1t)
{
  int c = blockIdx.x, r = threadIdx.x;
  float acc = b1[c];
  #pragma unroll
  for (int k = 0; k < 12; ++k) acc += feats[r*12 + k] * W1[k*64 + c];
  float mu = wred_add_all(acc) * (1.f/BB);
  float dv = acc - mu;
  float var = wred_add_all(dv*dv) * (1.f/BB);
  float scv = g1[c] * __frsqrt_rn(var + 1e-5f);
  // exact: gamma*(h-mu)/sqrt(var+eps)+beta; use precise sqrt for safety
  scv = g1[c] / sqrtf(var + 1e-5f);
  float v = dv*scv + be1[c];
  h1t[c*BB + r] = v > 0.f ? v : 0.f;
}

// mlp2: 128 blocks x 64 thr; block = column c of h2.
__global__ __launch_bounds__(64) void mlp2_kernel(const float* __restrict__ h1t,
    const float* __restrict__ W2, const float* __restrict__ b2,
    const float* __restrict__ g2, const float* __restrict__ be2,
    float* __restrict__ h2t)
{
  int c = blockIdx.x, r = threadIdx.x;
  float acc = b2[c];
  #pragma unroll 4
  for (int k = 0; k < 64; ++k) acc += h1t[k*BB + r] * W2[k*128 + c];
  float mu = wred_add_all(acc) * (1.f/BB);
  float dv = acc - mu;
  float var = wred_add_all(dv*dv) * (1.f/BB);
  float scv = g2[c] / sqrtf(var + 1e-5f);
  float v = dv*scv + be2[c];
  h2t[c*BB + r] = v > 0.f ? v : 0.f;
}

// mlp3: 128 blocks x 256 thr (4 waves); wave w -> output column c = blk*4+w.
__global__ __launch_bounds__(256) void mlp3_kernel(const float* __restrict__ h2t,
    const float* __restrict__ W3, const float* __restrict__ b3,
    float* __restrict__ out)
{
  int r = threadIdx.x & 63;
  int w = threadIdx.x >> 6;
  int c = blockIdx.x*4 + w;
  float acc = b3[c];
  #pragma unroll 4
  for (int k = 0; k < 128; ++k) acc += h2t[k*BB + r] * W3[k*512 + c];
  out[r*512 + c] = acc;
}

// ---------------- launch ----------------
extern "C" void kernel_launch(void* const* d_in, const int* in_sizes, int n_in,
                              void* d_out, int out_size, void* d_ws, size_t ws_size,
                              hipStream_t stream) {
  (void)in_sizes; (void)n_in; (void)out_size; (void)ws_size;
  const float* x   = (const float*)d_in[0];
  const float* W1  = (const float*)d_in[1];
  const float* b1  = (const float*)d_in[2];
  const float* g1  = (const float*)d_in[3];
  const float* be1 = (const float*)d_in[4];
  const float* W2  = (const float*)d_in[5];
  const float* b2  = (const float*)d_in[6];
  const float* g2  = (const float*)d_in[7];
  const float* be2 = (const float*)d_in[8];
  const float* W3  = (const float*)d_in[9];
  const float* b3  = (const float*)d_in[10];
  float* out = (float*)d_out;

  char* ws = (char*)d_ws;
  float2* bufc = (float2*)ws;
  float*  magc = (float*)(ws + 134217728);
  unsigned* hist1 = (unsigned*)(ws + 134217728 + 34078720);       // 168,296,448
  unsigned* hist2 = (unsigned*)(ws + 168296448 + 524288);         // 168,820,736
  char* sc = ws + 168820736 + 4194304;                            // 173,015,040
  unsigned* dmax      = (unsigned*)(sc + 0);
  unsigned* dmin      = (unsigned*)(sc + 256);
  double*   sum       = (double*)(sc + 512);
  double*   sumsq     = (double*)(sc + 1024);
  double*   qsum      = (double*)(sc + 1536);
  unsigned* cnt_half  = (unsigned*)(sc + 3584);
  unsigned* cnt_tenth = (unsigned*)(sc + 3840);
  unsigned* cnt_gtm   = (unsigned*)(sc + 4096);
  unsigned* sel1      = (unsigned*)(sc + 4352);
  unsigned* rem1      = (unsigned*)(sc + 4608);
  unsigned* medbits   = (unsigned*)(sc + 4864);
  float*    feats     = (float*)(sc + 5120);
  float*    h1t       = (float*)(sc + 8192);            // 64*64*4 = 16 KB
  float*    h2t       = (float*)(sc + 8192 + 16384);    // 128*64*4 = 32 KB

  hipMemsetAsync(hist1, 0, 524288 + 4194304, stream);
  hipMemsetAsync(sc, 0, 8192, stream);
  hipMemsetAsync(dmin, 0xFF, 256, stream);

  row_fft_kernel<<<BB*HH, 256, 0, stream>>>(x, bufc);
  col_fft_kernel<<<BB*17, 512, 0, stream>>>(bufc, magc, dmax, dmin, sum, sumsq, qsum, hist1);
  scan1_kernel<<<BB, 256, 0, stream>>>(hist1, sel1, rem1);
  pass2_kernel<<<dim3(BB, 4), 256, 0, stream>>>((const float4*)magc, sel1, sum, dmax,
      hist2, cnt_gtm, cnt_half, cnt_tenth);
  scan2_kernel<<<BB, 256, 0, stream>>>(hist2, sel1, rem1, medbits);
  feats_kernel<<<1, 64, 0, stream>>>(dmax, dmin, sum, sumsq, qsum, cnt_half, cnt_tenth, cnt_gtm, medbits, feats);
  mlp1_kernel<<<64, 64, 0, stream>>>(feats, W1, b1, g1, be1, h1t);
  mlp2_kernel<<<128, 64, 0, stream>>>(h1t, W2, b2, g2, be2, h2t);
  mlp3_kernel<<<128, 256, 0, stream>>>(h2t, W3, b3, out);
}

// Round 5
// 469.291 us; speedup vs baseline: 2.9922x; 1.0023x over previous
//
#include <hip/hip_runtime.h>
#include <math.h>

#ifndef M_PI
#define M_PI 3.14159265358979323846
#endif

#define BB 64
#define HH 512
#define WW 512
#define NPIX (HH*WW)        // 262144
#define MED_K 131072u       // 1-indexed rank of (n-1)//2
#define WS 260              // mag row stride (floats), cols 0..256 valid
#define PADI(i) ((i) + ((i) >> 5))

__device__ __forceinline__ float2 cmulf(float2 a, float2 b){
  return make_float2(a.x*b.x - a.y*b.y, a.x*b.y + a.y*b.x);
}
__device__ __forceinline__ unsigned rev9(unsigned v){ return __brev(v) >> 23; }

__device__ __forceinline__ double wred_add(double v){
  #pragma unroll
  for (int o = 32; o > 0; o >>= 1) v += __shfl_down(v, o, 64);
  return v;
}
__device__ __forceinline__ float wred_min(float v){
  #pragma unroll
  for (int o = 32; o > 0; o >>= 1) v = fminf(v, __shfl_down(v, o, 64));
  return v;
}
__device__ __forceinline__ float wred_max(float v){
  #pragma unroll
  for (int o = 32; o > 0; o >>= 1) v = fmaxf(v, __shfl_down(v, o, 64));
  return v;
}
__device__ __forceinline__ unsigned wred_addu(unsigned v){
  #pragma unroll
  for (int o = 32; o > 0; o >>= 1) v += __shfl_down(v, o, 64);
  return v;
}
__device__ __forceinline__ float wred_add_all(float v){
  #pragma unroll
  for (int o = 32; o > 0; o >>= 1) v += __shfl_xor(v, o, 64);
  return v;
}

// ---------------- twiddle init (once per call) ----------------
__global__ void twiddle_init_kernel(float2* __restrict__ twg){
  int t = threadIdx.x;  // 256
  double a = -2.0 * M_PI * (double)t / 512.0;
  twg[t] = make_float2((float)cos(a), (float)sin(a));
}

// ---------------- row FFT: 2 real rows packed into 1 complex FFT ----------------
// grid: BB*256 blocks (one per row pair), 256 threads.
__global__ __launch_bounds__(256) void row_fft_kernel(const float* __restrict__ x,
                                                      const float2* __restrict__ twg,
                                                      float2* __restrict__ out){
  __shared__ float sre[528], sim[528];
  __shared__ float2 tw[256];
  int t = threadIdx.x;
  tw[t] = twg[t];
  int pair = blockIdx.x;              // b*256 + hp
  int b = pair >> 8, hp = pair & 255;
  const float* base = x + (size_t)b*3*NPIX + (size_t)(2*hp)*WW;
  int rsel = t >> 7;                  // 0: row 2hp (-> re), 1: row 2hp+1 (-> im)
  int f4i = t & 127;
  const float* rowbase = base + rsel*WW;
  float4 rv = ((const float4*)rowbase)[f4i];
  float4 gv = ((const float4*)(rowbase + NPIX))[f4i];
  float4 bv = ((const float4*)(rowbase + 2*NPIX))[f4i];
  float g[4] = {0.299f*rv.x + 0.587f*gv.x + 0.114f*bv.x,
                0.299f*rv.y + 0.587f*gv.y + 0.114f*bv.y,
                0.299f*rv.z + 0.587f*gv.z + 0.114f*bv.z,
                0.299f*rv.w + 0.587f*gv.w + 0.114f*bv.w};
  int col0 = f4i << 2;
  #pragma unroll
  for (int q = 0; q < 4; ++q){
    int p = PADI((int)rev9((unsigned)(col0 + q)));
    if (rsel == 0) sre[p] = g[q]; else sim[p] = g[q];
  }
  __syncthreads();
  #pragma unroll
  for (int st = 1; st <= 9; ++st){
    int half = 1 << (st-1);
    int k = t & (half - 1);
    int i1 = ((t >> (st-1)) << st) + k;
    int i2 = i1 + half;
    int p1 = PADI(i1), p2 = PADI(i2);
    float2 w = tw[k << (9 - st)];
    float2 u = make_float2(sre[p1], sim[p1]);
    float2 raw = make_float2(sre[p2], sim[p2]);
    float2 v = cmulf(w, raw);
    sre[p1] = u.x + v.x; sim[p1] = u.y + v.y;
    sre[p2] = u.x - v.x; sim[p2] = u.y - v.y;
    __syncthreads();
  }
  // unpack: A[k] = 0.5(Z[k]+conj(Z[-k])), B[k] = -0.5i(Z[k]-conj(Z[-k])), k=0..256
  int row0 = (b << 9) + 2*hp;
  float2* o0 = out + (size_t)row0*WW;
  float2* o1 = o0 + WW;
  #pragma unroll
  for (int kk = 0; kk < 2; ++kk){
    int k = t + (kk << 8);
    if (k > 256) continue;
    int mk = (512 - k) & 511;
    int pk = PADI(k), pmk = PADI(mk);
    float zr = sre[pk], zi = sim[pk];
    float wr = sre[pmk], wi = sim[pmk];
    o0[k] = make_float2(0.5f*(zr + wr), 0.5f*(zi - wi));
    o1[k] = make_float2(0.5f*(zi + wi), 0.5f*(wr - zr));
  }
}

// ---------------- col FFT, 16-column tiles, fused stats + hist1 ----------------
__global__ __launch_bounds__(512) void col_fft_kernel(const float2* __restrict__ in,
    const float2* __restrict__ twg,
    float* __restrict__ magc,
    unsigned* __restrict__ dmax, unsigned* __restrict__ dmin,
    double* __restrict__ sum, double* __restrict__ sumsq, double* __restrict__ qsum,
    unsigned* __restrict__ hist1)
{
  __shared__ float2 s[512*16];
  __shared__ float2 tw[256];
  __shared__ unsigned h[2048];
  __shared__ double bufd[6][8];
  __shared__ float buff[2][8];
  int t = threadIdx.x;
  if (t < 256) tw[t] = twg[t];
  for (int i = t; i < 2048; i += 512) h[i] = 0;
  int b = blockIdx.x / 17;
  int j0 = (blockIdx.x % 17) << 4;
  const float2* base = in + (size_t)b*NPIX;
  for (int idx = t; idx < 512*16; idx += 512){
    int e = idx >> 4, c = idx & 15;
    int j = j0 + c;
    float2 v = (j <= 256) ? base[(size_t)e*WW + j] : make_float2(0.f, 0.f);
    s[(int)rev9((unsigned)e)*16 + c] = v;
  }
  __syncthreads();
  #pragma unroll
  for (int st = 1; st <= 9; ++st){
    int half = 1 << (st-1);
    #pragma unroll
    for (int qq = 0; qq < 8; ++qq){
      int tt = t + (qq << 9);
      int c = tt & 15;
      int kk = tt >> 4;
      int k = kk & (half - 1);
      int i1 = ((kk >> (st-1)) << st) + k;
      int i2 = i1 + half;
      float2 w = tw[k << (9 - st)];
      float2 u = s[i1*16 + c];
      float2 v = cmulf(w, s[i2*16 + c]);
      s[i1*16 + c] = make_float2(u.x + v.x, u.y + v.y);
      s[i2*16 + c] = make_float2(u.x - v.x, u.y - v.y);
    }
    __syncthreads();
  }
  double lsum=0.0, lsq=0.0, lq0=0.0, lq1=0.0, lq2=0.0, lq3=0.0;
  float lmn = 3.4e38f, lmx = 0.f;
  float* mo = magc + (size_t)b*(512*WS);
  for (int idx = t; idx < 512*16; idx += 512){
    int e = idx >> 4, c = idx & 15;
    int j = j0 + c;
    if (j > 256) continue;
    float2 v = s[e*16 + c];
    float m = sqrtf(v.x*v.x + v.y*v.y) + 1e-8f;
    int si = (e + 256) & 511;
    mo[(size_t)si*WS + j] = m;
    unsigned w = (j == 0 || j == 256) ? 1u : 2u;
    double md = (double)m;
    double wm = (w == 2u) ? md + md : md;
    lsum += wm;
    lsq  += wm * md;
    lmn = fminf(lmn, m); lmx = fmaxf(lmx, m);
    atomicAdd(&h[__float_as_uint(m) >> 20], w);
    int qa = si >> 7;
    lq0 += (qa==0)?md:0.0; lq1 += (qa==1)?md:0.0; lq2 += (qa==2)?md:0.0; lq3 += (qa==3)?md:0.0;
    if (w == 2u){
      int qb = ((512 - si) & 511) >> 7;
      lq0 += (qb==0)?md:0.0; lq1 += (qb==1)?md:0.0; lq2 += (qb==2)?md:0.0; lq3 += (qb==3)?md:0.0;
    }
  }
  int lane = t & 63, wv = t >> 6;
  double r0 = wred_add(lsum), r1 = wred_add(lsq);
  double r2 = wred_add(lq0), r3 = wred_add(lq1), r4 = wred_add(lq2), r5 = wred_add(lq3);
  float fmn = wred_min(lmn), fmx = wred_max(lmx);
  if (lane == 0){
    bufd[0][wv]=r0; bufd[1][wv]=r1; bufd[2][wv]=r2;
    bufd[3][wv]=r3; bufd[4][wv]=r4; bufd[5][wv]=r5;
    buff[0][wv]=fmn; buff[1][wv]=fmx;
  }
  __syncthreads();
  if (t == 0){
    double s0=0,s1=0,s2=0,s3=0,s4=0,s5=0; float mn=3.4e38f, mx=0.f;
    for (int i = 0; i < 8; ++i){
      s0+=bufd[0][i]; s1+=bufd[1][i]; s2+=bufd[2][i];
      s3+=bufd[3][i]; s4+=bufd[4][i]; s5+=bufd[5][i];
      mn=fminf(mn,buff[0][i]); mx=fmaxf(mx,buff[1][i]);
    }
    atomicAdd(sum + b, s0);
    atomicAdd(sumsq + b, s1);
    atomicAdd(qsum + b*4 + 0, s2);
    atomicAdd(qsum + b*4 + 1, s3);
    atomicAdd(qsum + b*4 + 2, s4);
    atomicAdd(qsum + b*4 + 3, s5);
    atomicMin(dmin + b, __float_as_uint(mn));
    atomicMax(dmax + b, __float_as_uint(mx));
  }
  unsigned* hb = hist1 + (size_t)b*2048;
  for (int i = t; i < 2048; i += 512){
    unsigned c = h[i];
    if (c) atomicAdd(&hb[i], c);
  }
}

__global__ void scan1_kernel(const unsigned* __restrict__ hist,
                             unsigned* __restrict__ sel, unsigned* __restrict__ rem){
  int b = blockIdx.x;
  const unsigned* hb = hist + (size_t)b*2048;
  __shared__ unsigned part[256];
  int t = threadIdx.x;
  unsigned s = 0;
  for (int i = 0; i < 8; ++i) s += hb[t*8 + i];
  part[t] = s; __syncthreads();
  if (t == 0){
    unsigned target = MED_K, cum = 0; int seg = 0;
    for (; seg < 256; ++seg){ if (cum + part[seg] >= target) break; cum += part[seg]; }
    unsigned r = target - cum;
    int bin = seg*8;
    for (;; ++bin){ unsigned c = hb[bin]; if (c >= r) break; r -= c; }
    sel[b] = (unsigned)bin;
    rem[b] = r;
  }
}

// pass2: grid (BB, 4); each block covers 128 rows of the compact mag plane.
__global__ __launch_bounds__(256) void pass2_kernel(const float4* __restrict__ magc4,
    const unsigned* __restrict__ sel1, const double* __restrict__ sum,
    const unsigned* __restrict__ dmax,
    unsigned* __restrict__ hist2, unsigned* __restrict__ cnt_gtm,
    unsigned* __restrict__ cnt_half, unsigned* __restrict__ cnt_tenth)
{
  __shared__ unsigned h[16384];
  __shared__ unsigned rb[3][8];
  int t = threadIdx.x, b = blockIdx.x;
  for (int i = t; i < 16384; i += 256) h[i] = 0;
  __syncthreads();
  unsigned s1 = sel1[b];
  float meanf = (float)(sum[b] / (double)NPIX);
  float d = __uint_as_float(dmax[b]) + 1e-8f;
  float th = 0.5f*d, tl = 0.1f*d;
  const float4* p = magc4 + (size_t)b*(512*(WS/4)) + (size_t)blockIdx.y*128*(WS/4);
  unsigned lgm = 0, lh = 0, lt = 0;
  for (int idx = t; idx < 128*(WS/4); idx += 256){
    float4 v = p[idx];
    int k = idx % (WS/4);
    int jc0 = k*4;
    float a[4] = {v.x, v.y, v.z, v.w};
    #pragma unroll
    for (int q = 0; q < 4; ++q){
      int jc = jc0 + q;
      if (jc > 256) continue;
      unsigned w = (jc == 0 || jc == 256) ? 1u : 2u;
      float m = a[q];
      unsigned bits = __float_as_uint(m);
      if ((bits >> 20) == s1) atomicAdd(&h[(bits >> 6) & 0x3fffu], w);
      lgm += (m > meanf) ? w : 0u;
      lh  += (m > th) ? w : 0u;
      lt  += (m > tl) ? w : 0u;
    }
  }
  int lane = t & 63, wv = t >> 6;
  unsigned g0 = wred_addu(lgm), g1 = wred_addu(lh), g2 = wred_addu(lt);
  if (lane == 0){ rb[0][wv]=g0; rb[1][wv]=g1; rb[2][wv]=g2; }
  __syncthreads();
  if (t == 0){
    unsigned a0=0,a1=0,a2=0;
    for (int i = 0; i < 4; ++i){ a0+=rb[0][i]; a1+=rb[1][i]; a2+=rb[2][i]; }
    atomicAdd(cnt_gtm + b, a0);
    atomicAdd(cnt_half + b, a1);
    atomicAdd(cnt_tenth + b, a2);
  }
  unsigned* hb = hist2 + (size_t)b*16384;
  for (int i = t; i < 16384; i += 256){
    unsigned c = h[i];
    if (c) atomicAdd(&hb[i], c);
  }
}

__global__ void scan2_kernel(const unsigned* __restrict__ hist,
    const unsigned* __restrict__ sel1, const unsigned* __restrict__ rem1,
    unsigned* __restrict__ medbits){
  int b = blockIdx.x;
  const unsigned* hb = hist + (size_t)b*16384;
  __shared__ unsigned part[256];
  int t = threadIdx.x;
  unsigned s = 0;
  for (int i = 0; i < 64; ++i) s += hb[t*64 + i];
  part[t] = s; __syncthreads();
  if (t == 0){
    unsigned target = rem1[b], cum = 0; int seg = 0;
    for (; seg < 256; ++seg){ if (cum + part[seg] >= target) break; cum += part[seg]; }
    unsigned r = target - cum;
    int bin = seg*64;
    for (;; ++bin){ unsigned c = hb[bin]; if (c >= r) break; r -= c; }
    medbits[b] = (sel1[b] << 20) | ((unsigned)bin << 6) | 32u;
  }
}

// ---------------- features ----------------
__global__ void feats_kernel(const unsigned* __restrict__ dmax, const unsigned* __restrict__ dmin,
    const double* __restrict__ sum, const double* __restrict__ sumsq, const double* __restrict__ qsum,
    const unsigned* __restrict__ cnt_half, const unsigned* __restrict__ cnt_tenth,
    const unsigned* __restrict__ cnt_gtmean, const unsigned* __restrict__ medbits,
    float* __restrict__ feats)
{
  int b = threadIdx.x;
  if (b >= BB) return;
  float maxv = __uint_as_float(dmax[b]);
  float d = maxv + 1e-8f;
  double dd = (double)d;
  double n = (double)NPIX;
  double sm = sum[b] / dd;
  double sq = sumsq[b] / (dd*dd);
  double mean = sm / n;
  double var = (sq - sm*sm/n) / (n - 1.0);
  if (var < 0.0) var = 0.0;
  float stdv = (float)sqrt(var);
  if (stdv < 1e-8f) stdv = 1e-8f;
  float mx = maxv / d;
  float mn = __uint_as_float(dmin[b]) / d;
  float gtm = (float)((double)cnt_gtmean[b] / n);
  float med = __uint_as_float(medbits[b]) / d;
  float q0 = (float)(qsum[b*4+0] / dd * (1.0/65536.0));
  float q1 = (float)(qsum[b*4+1] / dd * (1.0/65536.0));
  float q2 = (float)(qsum[b*4+2] / dd * (1.0/65536.0));
  float q3 = (float)(qsum[b*4+3] / dd * (1.0/65536.0));
  float gh = (float)((double)cnt_half[b] / n);
  float gt = (float)((double)cnt_tenth[b] / n);
  float f[12] = {(float)mean, stdv, mx, mn, gtm, med, q0, q1, q2, q3, gh, gt};
  #pragma unroll
  for (int i = 0; i < 12; ++i){
    float v = f[i];
    v = fminf(fmaxf(v, -10.f), 10.f);
    feats[b*12 + i] = v;
  }
}

// ---------------- MLP: column-parallel, BN per-column in one wave ----------------
__global__ __launch_bounds__(64) void mlp1_kernel(const float* __restrict__ feats,
    const float* __restrict__ W1, const float* __restrict__ b1,
    const float* __restrict__ g1, const float* __restrict__ be1,
    float* __restrict__ h1t)
{
  int c = blockIdx.x, r = threadIdx.x;
  float acc = b1[c];
  #pragma unroll
  for (int k = 0; k < 12; ++k) acc += feats[r*12 + k] * W1[k*64 + c];
  float mu = wred_add_all(acc) * (1.f/BB);
  float dv = acc - mu;
  float var = wred_add_all(dv*dv) * (1.f/BB);
  float scv = g1[c] / sqrtf(var + 1e-5f);
  float v = dv*scv + be1[c];
  h1t[c*BB + r] = v > 0.f ? v : 0.f;
}

__global__ __launch_bounds__(64) void mlp2_kernel(const float* __restrict__ h1t,
    const float* __restrict__ W2, const float* __restrict__ b2,
    const float* __restrict__ g2, const float* __restrict__ be2,
    float* __restrict__ h2t)
{
  int c = blockIdx.x, r = threadIdx.x;
  float acc = b2[c];
  #pragma unroll 4
  for (int k = 0; k < 64; ++k) acc += h1t[k*BB + r] * W2[k*128 + c];
  float mu = wred_add_all(acc) * (1.f/BB);
  float dv = acc - mu;
  float var = wred_add_all(dv*dv) * (1.f/BB);
  float scv = g2[c] / sqrtf(var + 1e-5f);
  float v = dv*scv + be2[c];
  h2t[c*BB + r] = v > 0.f ? v : 0.f;
}

__global__ __launch_bounds__(256) void mlp3_kernel(const float* __restrict__ h2t,
    const float* __restrict__ W3, const float* __restrict__ b3,
    float* __restrict__ out)
{
  int r = threadIdx.x & 63;
  int w = threadIdx.x >> 6;
  int c = blockIdx.x*4 + w;
  float acc = b3[c];
  #pragma unroll 4
  for (int k = 0; k < 128; ++k) acc += h2t[k*BB + r] * W3[k*512 + c];
  out[r*512 + c] = acc;
}

// ---------------- launch ----------------
extern "C" void kernel_launch(void* const* d_in, const int* in_sizes, int n_in,
                              void* d_out, int out_size, void* d_ws, size_t ws_size,
                              hipStream_t stream) {
  (void)in_sizes; (void)n_in; (void)out_size; (void)ws_size;
  const float* x   = (const float*)d_in[0];
  const float* W1  = (const float*)d_in[1];
  const float* b1  = (const float*)d_in[2];
  const float* g1  = (const float*)d_in[3];
  const float* be1 = (const float*)d_in[4];
  const float* W2  = (const float*)d_in[5];
  const float* b2  = (const float*)d_in[6];
  const float* g2  = (const float*)d_in[7];
  const float* be2 = (const float*)d_in[8];
  const float* W3  = (const float*)d_in[9];
  const float* b3  = (const float*)d_in[10];
  float* out = (float*)d_out;

  char* ws = (char*)d_ws;
  float2* bufc = (float2*)ws;
  float*  magc = (float*)(ws + 134217728);
  unsigned* hist1 = (unsigned*)(ws + 134217728 + 34078720);       // 168,296,448
  unsigned* hist2 = (unsigned*)(ws + 168296448 + 524288);         // 168,820,736
  char* sc = ws + 168820736 + 4194304;                            // 173,015,040
  unsigned* dmax      = (unsigned*)(sc + 0);
  unsigned* dmin      = (unsigned*)(sc + 256);
  double*   sum       = (double*)(sc + 512);
  double*   sumsq     = (double*)(sc + 1024);
  double*   qsum      = (double*)(sc + 1536);
  unsigned* cnt_half  = (unsigned*)(sc + 3584);
  unsigned* cnt_tenth = (unsigned*)(sc + 3840);
  unsigned* cnt_gtm   = (unsigned*)(sc + 4096);
  unsigned* sel1      = (unsigned*)(sc + 4352);
  unsigned* rem1      = (unsigned*)(sc + 4608);
  unsigned* medbits   = (unsigned*)(sc + 4864);
  float*    feats     = (float*)(sc + 5120);
  float*    h1t       = (float*)(sc + 8192);            // 16 KB
  float*    h2t       = (float*)(sc + 8192 + 16384);    // 32 KB
  float2*   twg       = (float2*)(sc + 8192 + 16384 + 32768);  // 2 KB

  hipMemsetAsync(hist1, 0, 524288 + 4194304, stream);
  hipMemsetAsync(sc, 0, 8192, stream);
  hipMemsetAsync(dmin, 0xFF, 256, stream);

  twiddle_init_kernel<<<1, 256, 0, stream>>>(twg);
  row_fft_kernel<<<BB*256, 256, 0, stream>>>(x, twg, bufc);
  col_fft_kernel<<<BB*17, 512, 0, stream>>>(bufc, twg, magc, dmax, dmin, sum, sumsq, qsum, hist1);
  scan1_kernel<<<BB, 256, 0, stream>>>(hist1, sel1, rem1);
  pass2_kernel<<<dim3(BB, 4), 256, 0, stream>>>((const float4*)magc, sel1, sum, dmax,
      hist2, cnt_gtm, cnt_half, cnt_tenth);
  scan2_kernel<<<BB, 256, 0, stream>>>(hist2, sel1, rem1, medbits);
  feats_kernel<<<1, 64, 0, stream>>>(dmax, dmin, sum, sumsq, qsum, cnt_half, cnt_tenth, cnt_gtm, medbits, feats);
  mlp1_kernel<<<64, 64, 0, stream>>>(feats, W1, b1, g1, be1, h1t);
  mlp2_kernel<<<128, 64, 0, stream>>>(h1t, W2, b2, g2, be2, h2t);
  mlp3_kernel<<<128, 256, 0, stream>>>(h2t, W3, b3, out);
}

// Round 6
// 468.979 us; speedup vs baseline: 2.9942x; 1.0007x over previous
//
#include <hip/hip_runtime.h>
#include <math.h>

#ifndef M_PI
#define M_PI 3.14159265358979323846
#endif

#define BB 64
#define HH 512
#define WW 512
#define NPIX (HH*WW)        // 262144
#define MED_K 131072u       // 1-indexed rank of (n-1)//2
#define WS 260              // mag row stride (floats), cols 0..256 valid
#define PADI(i) ((i) + ((i) >> 5))

__device__ __forceinline__ float2 cmulf(float2 a, float2 b){
  return make_float2(a.x*b.x - a.y*b.y, a.x*b.y + a.y*b.x);
}
__device__ __forceinline__ unsigned rev9(unsigned v){ return __brev(v) >> 23; }

__device__ __forceinline__ float wredf(float v){
  #pragma unroll
  for (int o = 32; o > 0; o >>= 1) v += __shfl_down(v, o, 64);
  return v;
}
__device__ __forceinline__ float wred_min(float v){
  #pragma unroll
  for (int o = 32; o > 0; o >>= 1) v = fminf(v, __shfl_down(v, o, 64));
  return v;
}
__device__ __forceinline__ float wred_max(float v){
  #pragma unroll
  for (int o = 32; o > 0; o >>= 1) v = fmaxf(v, __shfl_down(v, o, 64));
  return v;
}
__device__ __forceinline__ unsigned wred_addu(unsigned v){
  #pragma unroll
  for (int o = 32; o > 0; o >>= 1) v += __shfl_down(v, o, 64);
  return v;
}
__device__ __forceinline__ float wred_add_all(float v){
  #pragma unroll
  for (int o = 32; o > 0; o >>= 1) v += __shfl_xor(v, o, 64);
  return v;
}

// ---------------- init: twiddles + scalar block (replaces 2 memsets) ----------------
__global__ void init_kernel(float2* __restrict__ twg, unsigned* __restrict__ scal){
  int t = threadIdx.x;  // 256
  double a = -2.0 * M_PI * (double)t / 512.0;
  twg[t] = make_float2((float)cos(a), (float)sin(a));
  // scalar block: 8192 bytes = 2048 words; dmin occupies words 64..127 (0xFF), rest 0
  #pragma unroll
  for (int q = 0; q < 8; ++q){
    int w = t*8 + q;
    scal[w] = (w >= 64 && w < 128) ? 0xFFFFFFFFu : 0u;
  }
}

// ---------------- row FFT: 2 real rows packed into 1 complex FFT ----------------
__global__ __launch_bounds__(256) void row_fft_kernel(const float* __restrict__ x,
                                                      const float2* __restrict__ twg,
                                                      float2* __restrict__ out){
  __shared__ float sre[528], sim[528];
  __shared__ float2 tw[256];
  int t = threadIdx.x;
  tw[t] = twg[t];
  int pair = blockIdx.x;              // b*256 + hp
  int b = pair >> 8, hp = pair & 255;
  const float* base = x + (size_t)b*3*NPIX + (size_t)(2*hp)*WW;
  int rsel = t >> 7;                  // 0: row 2hp (-> re), 1: row 2hp+1 (-> im)
  int f4i = t & 127;
  const float* rowbase = base + rsel*WW;
  float4 rv = ((const float4*)rowbase)[f4i];
  float4 gv = ((const float4*)(rowbase + NPIX))[f4i];
  float4 bv = ((const float4*)(rowbase + 2*NPIX))[f4i];
  float g[4] = {0.299f*rv.x + 0.587f*gv.x + 0.114f*bv.x,
                0.299f*rv.y + 0.587f*gv.y + 0.114f*bv.y,
                0.299f*rv.z + 0.587f*gv.z + 0.114f*bv.z,
                0.299f*rv.w + 0.587f*gv.w + 0.114f*bv.w};
  int col0 = f4i << 2;
  #pragma unroll
  for (int q = 0; q < 4; ++q){
    int p = PADI((int)rev9((unsigned)(col0 + q)));
    if (rsel == 0) sre[p] = g[q]; else sim[p] = g[q];
  }
  __syncthreads();
  #pragma unroll
  for (int st = 1; st <= 9; ++st){
    int half = 1 << (st-1);
    int k = t & (half - 1);
    int i1 = ((t >> (st-1)) << st) + k;
    int i2 = i1 + half;
    int p1 = PADI(i1), p2 = PADI(i2);
    float2 w = tw[k << (9 - st)];
    float2 u = make_float2(sre[p1], sim[p1]);
    float2 raw = make_float2(sre[p2], sim[p2]);
    float2 v = cmulf(w, raw);
    sre[p1] = u.x + v.x; sim[p1] = u.y + v.y;
    sre[p2] = u.x - v.x; sim[p2] = u.y - v.y;
    __syncthreads();
  }
  int row0 = (b << 9) + 2*hp;
  float2* o0 = out + (size_t)row0*WW;
  float2* o1 = o0 + WW;
  #pragma unroll
  for (int kk = 0; kk < 2; ++kk){
    int k = t + (kk << 8);
    if (k > 256) continue;
    int mk = (512 - k) & 511;
    int pk = PADI(k), pmk = PADI(mk);
    float zr = sre[pk], zi = sim[pk];
    float wr = sre[pmk], wi = sim[pmk];
    o0[k] = make_float2(0.5f*(zr + wr), 0.5f*(zi - wi));
    o1[k] = make_float2(0.5f*(zi + wi), 0.5f*(wr - zr));
  }
}

// ---------------- col FFT, 16-column tiles, fused stats (f32) + hist1 ----------------
__global__ __launch_bounds__(512) void col_fft_kernel(const float2* __restrict__ in,
    const float2* __restrict__ twg,
    float* __restrict__ magc,
    unsigned* __restrict__ dmax, unsigned* __restrict__ dmin,
    double* __restrict__ sum, double* __restrict__ sumsq, double* __restrict__ qsum,
    unsigned* __restrict__ hist1)
{
  __shared__ float2 s[512*16];
  __shared__ float2 tw[256];
  __shared__ unsigned h[2048];
  __shared__ float buff[8][8];
  int t = threadIdx.x;
  if (t < 256) tw[t] = twg[t];
  for (int i = t; i < 2048; i += 512) h[i] = 0;
  int b = blockIdx.x / 17;
  int j0 = (blockIdx.x % 17) << 4;
  const float2* base = in + (size_t)b*NPIX;
  for (int idx = t; idx < 512*16; idx += 512){
    int e = idx >> 4, c = idx & 15;
    int j = j0 + c;
    float2 v = (j <= 256) ? base[(size_t)e*WW + j] : make_float2(0.f, 0.f);
    s[(int)rev9((unsigned)e)*16 + c] = v;
  }
  __syncthreads();
  #pragma unroll
  for (int st = 1; st <= 9; ++st){
    int half = 1 << (st-1);
    #pragma unroll
    for (int qq = 0; qq < 8; ++qq){
      int tt = t + (qq << 9);
      int c = tt & 15;
      int kk = tt >> 4;
      int k = kk & (half - 1);
      int i1 = ((kk >> (st-1)) << st) + k;
      int i2 = i1 + half;
      float2 w = tw[k << (9 - st)];
      float2 u = s[i1*16 + c];
      float2 v = cmulf(w, s[i2*16 + c]);
      s[i1*16 + c] = make_float2(u.x + v.x, u.y + v.y);
      s[i2*16 + c] = make_float2(u.x - v.x, u.y - v.y);
    }
    __syncthreads();
  }
  float lsum=0.f, lsq=0.f, lq0=0.f, lq1=0.f, lq2=0.f, lq3=0.f;
  float lmn = 3.4e38f, lmx = 0.f;
  float* mo = magc + (size_t)b*(512*WS);
  for (int idx = t; idx < 512*16; idx += 512){
    int e = idx >> 4, c = idx & 15;
    int j = j0 + c;
    if (j > 256) continue;
    float2 v = s[e*16 + c];
    float m = sqrtf(v.x*v.x + v.y*v.y) + 1e-8f;
    int si = (e + 256) & 511;
    mo[(size_t)si*WS + j] = m;
    unsigned w = (j == 0 || j == 256) ? 1u : 2u;
    float wm = (w == 2u) ? m + m : m;
    lsum += wm;
    lsq = fmaf(wm, m, lsq);
    lmn = fminf(lmn, m); lmx = fmaxf(lmx, m);
    atomicAdd(&h[__float_as_uint(m) >> 20], w);
    int qa = si >> 7;
    lq0 += (qa==0)?m:0.f; lq1 += (qa==1)?m:0.f; lq2 += (qa==2)?m:0.f; lq3 += (qa==3)?m:0.f;
    if (w == 2u){
      int qb = si ? 3 - ((si-1) >> 7) : 0;  // quadrant of mirror row (512-si)&511
      lq0 += (qb==0)?m:0.f; lq1 += (qb==1)?m:0.f; lq2 += (qb==2)?m:0.f; lq3 += (qb==3)?m:0.f;
    }
  }
  int lane = t & 63, wv = t >> 6;
  float r0 = wredf(lsum), r1 = wredf(lsq);
  float r2 = wredf(lq0), r3 = wredf(lq1), r4 = wredf(lq2), r5 = wredf(lq3);
  float fmn = wred_min(lmn), fmx = wred_max(lmx);
  if (lane == 0){
    buff[0][wv]=r0; buff[1][wv]=r1; buff[2][wv]=r2;
    buff[3][wv]=r3; buff[4][wv]=r4; buff[5][wv]=r5;
    buff[6][wv]=fmn; buff[7][wv]=fmx;
  }
  __syncthreads();
  if (t == 0){
    double s0=0,s1=0,s2=0,s3=0,s4=0,s5=0; float mn=3.4e38f, mx=0.f;
    for (int i = 0; i < 8; ++i){
      s0+=(double)buff[0][i]; s1+=(double)buff[1][i]; s2+=(double)buff[2][i];
      s3+=(double)buff[3][i]; s4+=(double)buff[4][i]; s5+=(double)buff[5][i];
      mn=fminf(mn,buff[6][i]); mx=fmaxf(mx,buff[7][i]);
    }
    atomicAdd(sum + b, s0);
    atomicAdd(sumsq + b, s1);
    atomicAdd(qsum + b*4 + 0, s2);
    atomicAdd(qsum + b*4 + 1, s3);
    atomicAdd(qsum + b*4 + 2, s4);
    atomicAdd(qsum + b*4 + 3, s5);
    atomicMin(dmin + b, __float_as_uint(mn));
    atomicMax(dmax + b, __float_as_uint(mx));
  }
  unsigned* hb = hist1 + (size_t)b*2048;
  for (int i = t; i < 2048; i += 512){
    unsigned c = h[i];
    if (c) atomicAdd(&hb[i], c);
  }
}

// ---------------- pass2: fused scan1 + fine hist + counts ----------------
// grid (BB, 4); each block covers 128 rows of the compact mag plane.
__global__ __launch_bounds__(256) void pass2_kernel(const float4* __restrict__ magc4,
    const unsigned* __restrict__ hist1, const double* __restrict__ sum,
    const unsigned* __restrict__ dmax,
    unsigned* __restrict__ hist2, unsigned* __restrict__ cnt_gtm,
    unsigned* __restrict__ cnt_half, unsigned* __restrict__ cnt_tenth)
{
  __shared__ unsigned h[16384];
  __shared__ unsigned part[256];
  __shared__ unsigned rb[3][8];
  __shared__ unsigned s_sel;
  int t = threadIdx.x, b = blockIdx.x;
  for (int i = t; i < 16384; i += 256) h[i] = 0;
  // fused scan1: derive sel1 from hist1[b]
  const unsigned* hb1 = hist1 + (size_t)b*2048;
  {
    unsigned sp = 0;
    #pragma unroll
    for (int i = 0; i < 8; ++i) sp += hb1[t*8 + i];
    part[t] = sp;
  }
  __syncthreads();
  if (t == 0){
    unsigned target = MED_K, cum = 0; int seg = 0;
    for (; seg < 256; ++seg){ if (cum + part[seg] >= target) break; cum += part[seg]; }
    unsigned r = target - cum;
    int bin = seg*8;
    for (;; ++bin){ unsigned c = hb1[bin]; if (c >= r) break; r -= c; }
    s_sel = (unsigned)bin;
  }
  __syncthreads();
  unsigned s1 = s_sel;
  float meanf = (float)(sum[b] / (double)NPIX);
  float d = __uint_as_float(dmax[b]) + 1e-8f;
  float th = 0.5f*d, tl = 0.1f*d;
  const float4* p = magc4 + (size_t)b*(512*(WS/4)) + (size_t)blockIdx.y*128*(WS/4);
  unsigned lgm = 0, lh = 0, lt = 0;
  for (int idx = t; idx < 128*(WS/4); idx += 256){
    float4 v = p[idx];
    int k = idx % (WS/4);
    int jc0 = k*4;
    float a[4] = {v.x, v.y, v.z, v.w};
    #pragma unroll
    for (int q = 0; q < 4; ++q){
      int jc = jc0 + q;
      if (jc > 256) continue;
      unsigned w = (jc == 0 || jc == 256) ? 1u : 2u;
      float m = a[q];
      unsigned bits = __float_as_uint(m);
      if ((bits >> 20) == s1) atomicAdd(&h[(bits >> 6) & 0x3fffu], w);
      lgm += (m > meanf) ? w : 0u;
      lh  += (m > th) ? w : 0u;
      lt  += (m > tl) ? w : 0u;
    }
  }
  int lane = t & 63, wv = t >> 6;
  unsigned g0 = wred_addu(lgm), g1 = wred_addu(lh), g2 = wred_addu(lt);
  if (lane == 0){ rb[0][wv]=g0; rb[1][wv]=g1; rb[2][wv]=g2; }
  __syncthreads();
  if (t == 0){
    unsigned a0=0,a1=0,a2=0;
    for (int i = 0; i < 4; ++i){ a0+=rb[0][i]; a1+=rb[1][i]; a2+=rb[2][i]; }
    atomicAdd(cnt_gtm + b, a0);
    atomicAdd(cnt_half + b, a1);
    atomicAdd(cnt_tenth + b, a2);
  }
  unsigned* hb = hist2 + (size_t)b*16384;
  for (int i = t; i < 16384; i += 256){
    unsigned c = h[i];
    if (c) atomicAdd(&hb[i], c);
  }
}

// ---------------- scan2 + feats fused: grid BB blocks x 256 thr ----------------
__global__ __launch_bounds__(256) void scan2_feats_kernel(
    const unsigned* __restrict__ hist1, const unsigned* __restrict__ hist2,
    const unsigned* __restrict__ dmax, const unsigned* __restrict__ dmin,
    const double* __restrict__ sum, const double* __restrict__ sumsq,
    const double* __restrict__ qsum,
    const unsigned* __restrict__ cnt_half, const unsigned* __restrict__ cnt_tenth,
    const unsigned* __restrict__ cnt_gtmean,
    float* __restrict__ feats)
{
  int b = blockIdx.x, t = threadIdx.x;
  __shared__ unsigned part[256];
  __shared__ unsigned s_sel, s_rem;
  // redo scan1 for sel1+rem1
  const unsigned* hb1 = hist1 + (size_t)b*2048;
  {
    unsigned sp = 0;
    #pragma unroll
    for (int i = 0; i < 8; ++i) sp += hb1[t*8 + i];
    part[t] = sp;
  }
  __syncthreads();
  if (t == 0){
    unsigned target = MED_K, cum = 0; int seg = 0;
    for (; seg < 256; ++seg){ if (cum + part[seg] >= target) break; cum += part[seg]; }
    unsigned r = target - cum;
    int bin = seg*8;
    for (;; ++bin){ unsigned c = hb1[bin]; if (c >= r) break; r -= c; }
    s_sel = (unsigned)bin; s_rem = r;
  }
  __syncthreads();
  // scan2 over hist2
  const unsigned* hb2 = hist2 + (size_t)b*16384;
  {
    unsigned sp = 0;
    for (int i = 0; i < 64; ++i) sp += hb2[t*64 + i];
    part[t] = sp;
  }
  __syncthreads();
  if (t == 0){
    unsigned target = s_rem, cum = 0; int seg = 0;
    for (; seg < 256; ++seg){ if (cum + part[seg] >= target) break; cum += part[seg]; }
    unsigned r = target - cum;
    int bin = seg*64;
    for (;; ++bin){ unsigned c = hb2[bin]; if (c >= r) break; r -= c; }
    unsigned medbits = (s_sel << 20) | ((unsigned)bin << 6) | 32u;
    // ---- feats (thread 0 only) ----
    float maxv = __uint_as_float(dmax[b]);
    float dd_f = maxv + 1e-8f;
    double dd = (double)dd_f;
    double n = (double)NPIX;
    double sm = sum[b] / dd;
    double sq = sumsq[b] / (dd*dd);
    double mean = sm / n;
    double var = (sq - sm*sm/n) / (n - 1.0);
    if (var < 0.0) var = 0.0;
    float stdv = (float)sqrt(var);
    if (stdv < 1e-8f) stdv = 1e-8f;
    float f[12];
    f[0] = (float)mean;
    f[1] = stdv;
    f[2] = maxv / dd_f;
    f[3] = __uint_as_float(dmin[b]) / dd_f;
    f[4] = (float)((double)cnt_gtmean[b] / n);
    f[5] = __uint_as_float(medbits) / dd_f;
    f[6] = (float)(qsum[b*4+0] / dd * (1.0/65536.0));
    f[7] = (float)(qsum[b*4+1] / dd * (1.0/65536.0));
    f[8] = (float)(qsum[b*4+2] / dd * (1.0/65536.0));
    f[9] = (float)(qsum[b*4+3] / dd * (1.0/65536.0));
    f[10] = (float)((double)cnt_half[b] / n);
    f[11] = (float)((double)cnt_tenth[b] / n);
    #pragma unroll
    for (int i = 0; i < 12; ++i)
      feats[b*12 + i] = fminf(fmaxf(f[i], -10.f), 10.f);
  }
}

// ---------------- MLP: column-parallel, BN per-column in one wave ----------------
__global__ __launch_bounds__(64) void mlp1_kernel(const float* __restrict__ feats,
    const float* __restrict__ W1, const float* __restrict__ b1,
    const float* __restrict__ g1, const float* __restrict__ be1,
    float* __restrict__ h1t)
{
  int c = blockIdx.x, r = threadIdx.x;
  float acc = b1[c];
  #pragma unroll
  for (int k = 0; k < 12; ++k) acc += feats[r*12 + k] * W1[k*64 + c];
  float mu = wred_add_all(acc) * (1.f/BB);
  float dv = acc - mu;
  float var = wred_add_all(dv*dv) * (1.f/BB);
  float scv = g1[c] / sqrtf(var + 1e-5f);
  float v = dv*scv + be1[c];
  h1t[c*BB + r] = v > 0.f ? v : 0.f;
}

__global__ __launch_bounds__(64) void mlp2_kernel(const float* __restrict__ h1t,
    const float* __restrict__ W2, const float* __restrict__ b2,
    const float* __restrict__ g2, const float* __restrict__ be2,
    float* __restrict__ h2t)
{
  int c = blockIdx.x, r = threadIdx.x;
  float acc = b2[c];
  #pragma unroll 4
  for (int k = 0; k < 64; ++k) acc += h1t[k*BB + r] * W2[k*128 + c];
  float mu = wred_add_all(acc) * (1.f/BB);
  float dv = acc - mu;
  float var = wred_add_all(dv*dv) * (1.f/BB);
  float scv = g2[c] / sqrtf(var + 1e-5f);
  float v = dv*scv + be2[c];
  h2t[c*BB + r] = v > 0.f ? v : 0.f;
}

__global__ __launch_bounds__(256) void mlp3_kernel(const float* __restrict__ h2t,
    const float* __restrict__ W3, const float* __restrict__ b3,
    float* __restrict__ out)
{
  int r = threadIdx.x & 63;
  int w = threadIdx.x >> 6;
  int c = blockIdx.x*4 + w;
  float acc = b3[c];
  #pragma unroll 4
  for (int k = 0; k < 128; ++k) acc += h2t[k*BB + r] * W3[k*512 + c];
  out[r*512 + c] = acc;
}

// ---------------- launch ----------------
extern "C" void kernel_launch(void* const* d_in, const int* in_sizes, int n_in,
                              void* d_out, int out_size, void* d_ws, size_t ws_size,
                              hipStream_t stream) {
  (void)in_sizes; (void)n_in; (void)out_size; (void)ws_size;
  const float* x   = (const float*)d_in[0];
  const float* W1  = (const float*)d_in[1];
  const float* b1  = (const float*)d_in[2];
  const float* g1  = (const float*)d_in[3];
  const float* be1 = (const float*)d_in[4];
  const float* W2  = (const float*)d_in[5];
  const float* b2  = (const float*)d_in[6];
  const float* g2  = (const float*)d_in[7];
  const float* be2 = (const float*)d_in[8];
  const float* W3  = (const float*)d_in[9];
  const float* b3  = (const float*)d_in[10];
  float* out = (float*)d_out;

  char* ws = (char*)d_ws;
  float2* bufc = (float2*)ws;
  float*  magc = (float*)(ws + 134217728);
  unsigned* hist1 = (unsigned*)(ws + 134217728 + 34078720);       // 168,296,448
  unsigned* hist2 = (unsigned*)(ws + 168296448 + 524288);         // 168,820,736
  char* sc = ws + 168820736 + 4194304;                            // 173,015,040
  unsigned* dmax      = (unsigned*)(sc + 0);
  unsigned* dmin      = (unsigned*)(sc + 256);     // words 64..127 of scalar block
  double*   sum       = (double*)(sc + 512);
  double*   sumsq     = (double*)(sc + 1024);
  double*   qsum      = (double*)(sc + 1536);
  unsigned* cnt_half  = (unsigned*)(sc + 3584);
  unsigned* cnt_tenth = (unsigned*)(sc + 3840);
  unsigned* cnt_gtm   = (unsigned*)(sc + 4096);
  float*    feats     = (float*)(sc + 5120);
  float*    h1t       = (float*)(sc + 8192);            // 16 KB
  float*    h2t       = (float*)(sc + 8192 + 16384);    // 32 KB
  float2*   twg       = (float2*)(sc + 8192 + 16384 + 32768);  // 2 KB

  hipMemsetAsync(hist1, 0, 524288 + 4194304, stream);   // hist1+hist2 contiguous

  init_kernel<<<1, 256, 0, stream>>>(twg, (unsigned*)sc);
  row_fft_kernel<<<BB*256, 256, 0, stream>>>(x, twg, bufc);
  col_fft_kernel<<<BB*17, 512, 0, stream>>>(bufc, twg, magc, dmax, dmin, sum, sumsq, qsum, hist1);
  pass2_kernel<<<dim3(BB, 4), 256, 0, stream>>>((const float4*)magc, hist1, sum, dmax,
      hist2, cnt_gtm, cnt_half, cnt_tenth);
  scan2_feats_kernel<<<BB, 256, 0, stream>>>(hist1, hist2, dmax, dmin, sum, sumsq, qsum,
      cnt_half, cnt_tenth, cnt_gtm, feats);
  mlp1_kernel<<<64, 64, 0, stream>>>(feats, W1, b1, g1, be1, h1t);
  mlp2_kernel<<<128, 64, 0, stream>>>(h1t, W2, b2, g2, be2, h2t);
  mlp3_kernel<<<128, 256, 0, stream>>>(h2t, W3, b3, out);
}

// Round 7
// 461.830 us; speedup vs baseline: 3.0406x; 1.0155x over previous
//
#include <hip/hip_runtime.h>
#include <math.h>

#ifndef M_PI
#define M_PI 3.14159265358979323846
#endif

#define BB 64
#define HH 512
#define WW 512
#define NPIX (HH*WW)        // 262144
#define MED_K 131072u       // 1-indexed rank of (n-1)//2
#define WS 260              // mag row stride (floats), cols 0..256 valid
#define PADI(i) ((i) + ((i) >> 5))

__device__ __forceinline__ float2 cmulf(float2 a, float2 b){
  return make_float2(a.x*b.x - a.y*b.y, a.x*b.y + a.y*b.x);
}
__device__ __forceinline__ unsigned rev9(unsigned v){ return __brev(v) >> 23; }

__device__ __forceinline__ float wredf(float v){
  #pragma unroll
  for (int o = 32; o > 0; o >>= 1) v += __shfl_down(v, o, 64);
  return v;
}
__device__ __forceinline__ float wred_min(float v){
  #pragma unroll
  for (int o = 32; o > 0; o >>= 1) v = fminf(v, __shfl_down(v, o, 64));
  return v;
}
__device__ __forceinline__ float wred_max(float v){
  #pragma unroll
  for (int o = 32; o > 0; o >>= 1) v = fmaxf(v, __shfl_down(v, o, 64));
  return v;
}
__device__ __forceinline__ unsigned wred_addu(unsigned v){
  #pragma unroll
  for (int o = 32; o > 0; o >>= 1) v += __shfl_down(v, o, 64);
  return v;
}
__device__ __forceinline__ float wred_add_all(float v){
  #pragma unroll
  for (int o = 32; o > 0; o >>= 1) v += __shfl_xor(v, o, 64);
  return v;
}

// ---------------- init: twiddles + scalar block ----------------
__global__ void init_kernel(float2* __restrict__ twg, unsigned* __restrict__ scal){
  int t = threadIdx.x;  // 256
  double a = -2.0 * M_PI * (double)t / 512.0;
  twg[t] = make_float2((float)cos(a), (float)sin(a));
  #pragma unroll
  for (int q = 0; q < 8; ++q){
    int w = t*8 + q;
    scal[w] = (w >= 64 && w < 128) ? 0xFFFFFFFFu : 0u;
  }
}

// ---------------- row FFT: 2 real rows packed into 1 complex FFT ----------------
__global__ __launch_bounds__(256) void row_fft_kernel(const float* __restrict__ x,
                                                      const float2* __restrict__ twg,
                                                      float2* __restrict__ out){
  __shared__ float sre[528], sim[528];
  __shared__ float2 tw[256];
  int t = threadIdx.x;
  tw[t] = twg[t];
  int pair = blockIdx.x;              // b*256 + hp
  int b = pair >> 8, hp = pair & 255;
  const float* base = x + (size_t)b*3*NPIX + (size_t)(2*hp)*WW;
  int rsel = t >> 7;
  int f4i = t & 127;
  const float* rowbase = base + rsel*WW;
  float4 rv = ((const float4*)rowbase)[f4i];
  float4 gv = ((const float4*)(rowbase + NPIX))[f4i];
  float4 bv = ((const float4*)(rowbase + 2*NPIX))[f4i];
  float g[4] = {0.299f*rv.x + 0.587f*gv.x + 0.114f*bv.x,
                0.299f*rv.y + 0.587f*gv.y + 0.114f*bv.y,
                0.299f*rv.z + 0.587f*gv.z + 0.114f*bv.z,
                0.299f*rv.w + 0.587f*gv.w + 0.114f*bv.w};
  int col0 = f4i << 2;
  #pragma unroll
  for (int q = 0; q < 4; ++q){
    int p = PADI((int)rev9((unsigned)(col0 + q)));
    if (rsel == 0) sre[p] = g[q]; else sim[p] = g[q];
  }
  __syncthreads();
  #pragma unroll
  for (int st = 1; st <= 9; ++st){
    int half = 1 << (st-1);
    int k = t & (half - 1);
    int i1 = ((t >> (st-1)) << st) + k;
    int i2 = i1 + half;
    int p1 = PADI(i1), p2 = PADI(i2);
    float2 w = tw[k << (9 - st)];
    float2 u = make_float2(sre[p1], sim[p1]);
    float2 raw = make_float2(sre[p2], sim[p2]);
    float2 v = cmulf(w, raw);
    sre[p1] = u.x + v.x; sim[p1] = u.y + v.y;
    sre[p2] = u.x - v.x; sim[p2] = u.y - v.y;
    __syncthreads();
  }
  int row0 = (b << 9) + 2*hp;
  float2* o0 = out + (size_t)row0*WW;
  float2* o1 = o0 + WW;
  #pragma unroll
  for (int kk = 0; kk < 2; ++kk){
    int k = t + (kk << 8);
    if (k > 256) continue;
    int mk = (512 - k) & 511;
    int pk = PADI(k), pmk = PADI(mk);
    float zr = sre[pk], zi = sim[pk];
    float wr = sre[pmk], wi = sim[pmk];
    o0[k] = make_float2(0.5f*(zr + wr), 0.5f*(zi - wi));
    o1[k] = make_float2(0.5f*(zi + wi), 0.5f*(wr - zr));
  }
}

// ---------------- col FFT: fused stats + per-wave privatized 256-bin exp hist ----------------
__global__ __launch_bounds__(512) void col_fft_kernel(const float2* __restrict__ in,
    const float2* __restrict__ twg,
    float* __restrict__ magc,
    unsigned* __restrict__ dmax, unsigned* __restrict__ dmin,
    double* __restrict__ sum, double* __restrict__ sumsq, double* __restrict__ qsum,
    unsigned* __restrict__ hist1)
{
  __shared__ float2 s[512*16];
  __shared__ float2 tw[256];
  __shared__ unsigned h[8*256];       // per-wave privatized exponent histogram
  __shared__ float buff[8][8];
  int t = threadIdx.x;
  if (t < 256) tw[t] = twg[t];
  for (int i = t; i < 2048; i += 512) h[i] = 0;
  int b = blockIdx.x / 17;
  int j0 = (blockIdx.x % 17) << 4;
  const float2* base = in + (size_t)b*NPIX;
  for (int idx = t; idx < 512*16; idx += 512){
    int e = idx >> 4, c = idx & 15;
    int j = j0 + c;
    float2 v = (j <= 256) ? base[(size_t)e*WW + j] : make_float2(0.f, 0.f);
    s[(int)rev9((unsigned)e)*16 + c] = v;
  }
  __syncthreads();
  #pragma unroll
  for (int st = 1; st <= 9; ++st){
    int half = 1 << (st-1);
    #pragma unroll
    for (int qq = 0; qq < 8; ++qq){
      int tt = t + (qq << 9);
      int c = tt & 15;
      int kk = tt >> 4;
      int k = kk & (half - 1);
      int i1 = ((kk >> (st-1)) << st) + k;
      int i2 = i1 + half;
      float2 w = tw[k << (9 - st)];
      float2 u = s[i1*16 + c];
      float2 v = cmulf(w, s[i2*16 + c]);
      s[i1*16 + c] = make_float2(u.x + v.x, u.y + v.y);
      s[i2*16 + c] = make_float2(u.x - v.x, u.y - v.y);
    }
    __syncthreads();
  }
  float lsum=0.f, lsq=0.f, lq0=0.f, lq1=0.f, lq2=0.f, lq3=0.f;
  float lmn = 3.4e38f, lmx = 0.f;
  int wv = t >> 6, lane = t & 63;
  unsigned* hw = h + (wv << 8);       // this wave's private copy
  float* mo = magc + (size_t)b*(512*WS);
  for (int idx = t; idx < 512*16; idx += 512){
    int e = idx >> 4, c = idx & 15;
    int j = j0 + c;
    if (j > 256) continue;
    float2 v = s[e*16 + c];
    float m = sqrtf(v.x*v.x + v.y*v.y) + 1e-8f;
    int si = (e + 256) & 511;
    mo[(size_t)si*WS + j] = m;
    unsigned w = (j == 0 || j == 256) ? 1u : 2u;
    float wm = (w == 2u) ? m + m : m;
    lsum += wm;
    lsq = fmaf(wm, m, lsq);
    lmn = fminf(lmn, m); lmx = fmaxf(lmx, m);
    atomicAdd(&hw[__float_as_uint(m) >> 23], w);
    int qa = si >> 7;
    lq0 += (qa==0)?m:0.f; lq1 += (qa==1)?m:0.f; lq2 += (qa==2)?m:0.f; lq3 += (qa==3)?m:0.f;
    if (w == 2u){
      int qb = si ? 3 - ((si-1) >> 7) : 0;
      lq0 += (qb==0)?m:0.f; lq1 += (qb==1)?m:0.f; lq2 += (qb==2)?m:0.f; lq3 += (qb==3)?m:0.f;
    }
  }
  float r0 = wredf(lsum), r1 = wredf(lsq);
  float r2 = wredf(lq0), r3 = wredf(lq1), r4 = wredf(lq2), r5 = wredf(lq3);
  float fmn = wred_min(lmn), fmx = wred_max(lmx);
  if (lane == 0){
    buff[0][wv]=r0; buff[1][wv]=r1; buff[2][wv]=r2;
    buff[3][wv]=r3; buff[4][wv]=r4; buff[5][wv]=r5;
    buff[6][wv]=fmn; buff[7][wv]=fmx;
  }
  __syncthreads();
  if (t == 0){
    double s0=0,s1=0,s2=0,s3=0,s4=0,s5=0; float mn=3.4e38f, mx=0.f;
    for (int i = 0; i < 8; ++i){
      s0+=(double)buff[0][i]; s1+=(double)buff[1][i]; s2+=(double)buff[2][i];
      s3+=(double)buff[3][i]; s4+=(double)buff[4][i]; s5+=(double)buff[5][i];
      mn=fminf(mn,buff[6][i]); mx=fmaxf(mx,buff[7][i]);
    }
    atomicAdd(sum + b, s0);
    atomicAdd(sumsq + b, s1);
    atomicAdd(qsum + b*4 + 0, s2);
    atomicAdd(qsum + b*4 + 1, s3);
    atomicAdd(qsum + b*4 + 2, s4);
    atomicAdd(qsum + b*4 + 3, s5);
    atomicMin(dmin + b, __float_as_uint(mn));
    atomicMax(dmax + b, __float_as_uint(mx));
  }
  // merge 8 private copies -> global 256-bin hist
  unsigned* hb = hist1 + (size_t)b*256;
  if (t < 256){
    unsigned c = h[t] + h[256+t] + h[512+t] + h[768+t]
               + h[1024+t] + h[1280+t] + h[1536+t] + h[1792+t];
    if (c) atomicAdd(&hb[t], c);
  }
}

// ---------------- pass2: fused scan1 (256-bin) + fine mantissa hist + counts ----------------
// grid (BB, 4); each block covers 128 rows of the compact mag plane.
__global__ __launch_bounds__(256) void pass2_kernel(const float4* __restrict__ magc4,
    const unsigned* __restrict__ hist1, const double* __restrict__ sum,
    const unsigned* __restrict__ dmax,
    unsigned* __restrict__ hist2, unsigned* __restrict__ cnt_gtm,
    unsigned* __restrict__ cnt_half, unsigned* __restrict__ cnt_tenth)
{
  __shared__ unsigned h[16384];
  __shared__ unsigned part[256];
  __shared__ unsigned rb[3][8];
  __shared__ unsigned s_sel;
  int t = threadIdx.x, b = blockIdx.x;
  for (int i = t; i < 16384; i += 256) h[i] = 0;
  const unsigned* hb1 = hist1 + (size_t)b*256;
  part[t] = hb1[t];
  __syncthreads();
  if (t == 0){
    unsigned target = MED_K, cum = 0; int bin = 0;
    for (; bin < 256; ++bin){ if (cum + part[bin] >= target) break; cum += part[bin]; }
    s_sel = (unsigned)bin;
  }
  __syncthreads();
  unsigned s1 = s_sel;
  float meanf = (float)(sum[b] / (double)NPIX);
  float d = __uint_as_float(dmax[b]) + 1e-8f;
  float th = 0.5f*d, tl = 0.1f*d;
  const float4* p = magc4 + (size_t)b*(512*(WS/4)) + (size_t)blockIdx.y*128*(WS/4);
  unsigned lgm = 0, lh = 0, lt = 0;
  for (int idx = t; idx < 128*(WS/4); idx += 256){
    float4 v = p[idx];
    int k = idx % (WS/4);
    int jc0 = k*4;
    float a[4] = {v.x, v.y, v.z, v.w};
    #pragma unroll
    for (int q = 0; q < 4; ++q){
      int jc = jc0 + q;
      if (jc > 256) continue;
      unsigned w = (jc == 0 || jc == 256) ? 1u : 2u;
      float m = a[q];
      unsigned bits = __float_as_uint(m);
      if ((bits >> 23) == s1) atomicAdd(&h[(bits >> 9) & 0x3fffu], w);
      lgm += (m > meanf) ? w : 0u;
      lh  += (m > th) ? w : 0u;
      lt  += (m > tl) ? w : 0u;
    }
  }
  int lane = t & 63, wv = t >> 6;
  unsigned g0 = wred_addu(lgm), g1 = wred_addu(lh), g2 = wred_addu(lt);
  if (lane == 0){ rb[0][wv]=g0; rb[1][wv]=g1; rb[2][wv]=g2; }
  __syncthreads();
  if (t == 0){
    unsigned a0=0,a1=0,a2=0;
    for (int i = 0; i < 4; ++i){ a0+=rb[0][i]; a1+=rb[1][i]; a2+=rb[2][i]; }
    atomicAdd(cnt_gtm + b, a0);
    atomicAdd(cnt_half + b, a1);
    atomicAdd(cnt_tenth + b, a2);
  }
  unsigned* hb = hist2 + (size_t)b*16384;
  for (int i = t; i < 16384; i += 256){
    unsigned c = h[i];
    if (c) atomicAdd(&hb[i], c);
  }
}

// ---------------- scan2 + feats fused ----------------
__global__ __launch_bounds__(256) void scan2_feats_kernel(
    const unsigned* __restrict__ hist1, const unsigned* __restrict__ hist2,
    const unsigned* __restrict__ dmax, const unsigned* __restrict__ dmin,
    const double* __restrict__ sum, const double* __restrict__ sumsq,
    const double* __restrict__ qsum,
    const unsigned* __restrict__ cnt_half, const unsigned* __restrict__ cnt_tenth,
    const unsigned* __restrict__ cnt_gtmean,
    float* __restrict__ feats)
{
  int b = blockIdx.x, t = threadIdx.x;
  __shared__ unsigned part[256];
  __shared__ unsigned s_sel, s_rem;
  const unsigned* hb1 = hist1 + (size_t)b*256;
  part[t] = hb1[t];
  __syncthreads();
  if (t == 0){
    unsigned target = MED_K, cum = 0; int bin = 0;
    for (; bin < 256; ++bin){ if (cum + part[bin] >= target) break; cum += part[bin]; }
    s_sel = (unsigned)bin; s_rem = target - cum;
  }
  __syncthreads();
  const unsigned* hb2 = hist2 + (size_t)b*16384;
  {
    unsigned sp = 0;
    for (int i = 0; i < 64; ++i) sp += hb2[t*64 + i];
    part[t] = sp;
  }
  __syncthreads();
  if (t == 0){
    unsigned target = s_rem, cum = 0; int seg = 0;
    for (; seg < 256; ++seg){ if (cum + part[seg] >= target) break; cum += part[seg]; }
    unsigned r = target - cum;
    int bin = seg*64;
    for (;; ++bin){ unsigned c = hb2[bin]; if (c >= r) break; r -= c; }
    unsigned medbits = (s_sel << 23) | ((unsigned)bin << 9) | 256u;  // mantissa midpoint
    float maxv = __uint_as_float(dmax[b]);
    float dd_f = maxv + 1e-8f;
    double dd = (double)dd_f;
    double n = (double)NPIX;
    double sm = sum[b] / dd;
    double sq = sumsq[b] / (dd*dd);
    double mean = sm / n;
    double var = (sq - sm*sm/n) / (n - 1.0);
    if (var < 0.0) var = 0.0;
    float stdv = (float)sqrt(var);
    if (stdv < 1e-8f) stdv = 1e-8f;
    float f[12];
    f[0] = (float)mean;
    f[1] = stdv;
    f[2] = maxv / dd_f;
    f[3] = __uint_as_float(dmin[b]) / dd_f;
    f[4] = (float)((double)cnt_gtmean[b] / n);
    f[5] = __uint_as_float(medbits) / dd_f;
    f[6] = (float)(qsum[b*4+0] / dd * (1.0/65536.0));
    f[7] = (float)(qsum[b*4+1] / dd * (1.0/65536.0));
    f[8] = (float)(qsum[b*4+2] / dd * (1.0/65536.0));
    f[9] = (float)(qsum[b*4+3] / dd * (1.0/65536.0));
    f[10] = (float)((double)cnt_half[b] / n);
    f[11] = (float)((double)cnt_tenth[b] / n);
    #pragma unroll
    for (int i = 0; i < 12; ++i)
      feats[b*12 + i] = fminf(fmaxf(f[i], -10.f), 10.f);
  }
}

// ---------------- MLP: column-parallel, BN per-column in one wave ----------------
__global__ __launch_bounds__(64) void mlp1_kernel(const float* __restrict__ feats,
    const float* __restrict__ W1, const float* __restrict__ b1,
    const float* __restrict__ g1, const float* __restrict__ be1,
    float* __restrict__ h1t)
{
  int c = blockIdx.x, r = threadIdx.x;
  float acc = b1[c];
  #pragma unroll
  for (int k = 0; k < 12; ++k) acc += feats[r*12 + k] * W1[k*64 + c];
  float mu = wred_add_all(acc) * (1.f/BB);
  float dv = acc - mu;
  float var = wred_add_all(dv*dv) * (1.f/BB);
  float scv = g1[c] / sqrtf(var + 1e-5f);
  float v = dv*scv + be1[c];
  h1t[c*BB + r] = v > 0.f ? v : 0.f;
}

__global__ __launch_bounds__(64) void mlp2_kernel(const float* __restrict__ h1t,
    const float* __restrict__ W2, const float* __restrict__ b2,
    const float* __restrict__ g2, const float* __restrict__ be2,
    float* __restrict__ h2t)
{
  int c = blockIdx.x, r = threadIdx.x;
  float acc = b2[c];
  #pragma unroll 4
  for (int k = 0; k < 64; ++k) acc += h1t[k*BB + r] * W2[k*128 + c];
  float mu = wred_add_all(acc) * (1.f/BB);
  float dv = acc - mu;
  float var = wred_add_all(dv*dv) * (1.f/BB);
  float scv = g2[c] / sqrtf(var + 1e-5f);
  float v = dv*scv + be2[c];
  h2t[c*BB + r] = v > 0.f ? v : 0.f;
}

__global__ __launch_bounds__(256) void mlp3_kernel(const float* __restrict__ h2t,
    const float* __restrict__ W3, const float* __restrict__ b3,
    float* __restrict__ out)
{
  int r = threadIdx.x & 63;
  int w = threadIdx.x >> 6;
  int c = blockIdx.x*4 + w;
  float acc = b3[c];
  #pragma unroll 4
  for (int k = 0; k < 128; ++k) acc += h2t[k*BB + r] * W3[k*512 + c];
  out[r*512 + c] = acc;
}

// ---------------- launch ----------------
extern "C" void kernel_launch(void* const* d_in, const int* in_sizes, int n_in,
                              void* d_out, int out_size, void* d_ws, size_t ws_size,
                              hipStream_t stream) {
  (void)in_sizes; (void)n_in; (void)out_size; (void)ws_size;
  const float* x   = (const float*)d_in[0];
  const float* W1  = (const float*)d_in[1];
  const float* b1  = (const float*)d_in[2];
  const float* g1  = (const float*)d_in[3];
  const float* be1 = (const float*)d_in[4];
  const float* W2  = (const float*)d_in[5];
  const float* b2  = (const float*)d_in[6];
  const float* g2  = (const float*)d_in[7];
  const float* be2 = (const float*)d_in[8];
  const float* W3  = (const float*)d_in[9];
  const float* b3  = (const float*)d_in[10];
  float* out = (float*)d_out;

  char* ws = (char*)d_ws;
  float2* bufc = (float2*)ws;
  float*  magc = (float*)(ws + 134217728);
  unsigned* hist1 = (unsigned*)(ws + 134217728 + 34078720);       // 168,296,448 (64 KB)
  unsigned* hist2 = (unsigned*)(ws + 168296448 + 65536);          // 168,361,984 (4 MB)
  char* sc = ws + 168361984 + 4194304;                            // 172,556,288
  unsigned* dmax      = (unsigned*)(sc + 0);
  unsigned* dmin      = (unsigned*)(sc + 256);
  double*   sum       = (double*)(sc + 512);
  double*   sumsq     = (double*)(sc + 1024);
  double*   qsum      = (double*)(sc + 1536);
  unsigned* cnt_half  = (unsigned*)(sc + 3584);
  unsigned* cnt_tenth = (unsigned*)(sc + 3840);
  unsigned* cnt_gtm   = (unsigned*)(sc + 4096);
  float*    feats     = (float*)(sc + 5120);
  float*    h1t       = (float*)(sc + 8192);            // 16 KB
  float*    h2t       = (float*)(sc + 8192 + 16384);    // 32 KB
  float2*   twg       = (float2*)(sc + 8192 + 16384 + 32768);  // 2 KB

  hipMemsetAsync(hist1, 0, 65536 + 4194304, stream);   // hist1+hist2 contiguous

  init_kernel<<<1, 256, 0, stream>>>(twg, (unsigned*)sc);
  row_fft_kernel<<<BB*256, 256, 0, stream>>>(x, twg, bufc);
  col_fft_kernel<<<BB*17, 512, 0, stream>>>(bufc, twg, magc, dmax, dmin, sum, sumsq, qsum, hist1);
  pass2_kernel<<<dim3(BB, 4), 256, 0, stream>>>((const float4*)magc, hist1, sum, dmax,
      hist2, cnt_gtm, cnt_half, cnt_tenth);
  scan2_feats_kernel<<<BB, 256, 0, stream>>>(hist1, hist2, dmax, dmin, sum, sumsq, qsum,
      cnt_half, cnt_tenth, cnt_gtm, feats);
  mlp1_kernel<<<64, 64, 0, stream>>>(feats, W1, b1, g1, be1, h1t);
  mlp2_kernel<<<128, 64, 0, stream>>>(h1t, W2, b2, g2, be2, h2t);
  mlp3_kernel<<<128, 256, 0, stream>>>(h2t, W3, b3, out);
}